// Round 9
// baseline (290.730 us; speedup 1.0000x reference)
//
#include <hip/hip_runtime.h>
#include <hip/hip_bf16.h>
#include <math.h>

#define BB 16
#define NPT 4096
#define CH 32
#define MX 24      // kx count
#define MYK 23     // ky count
#define NF 288
#define NS 16      // fwd K-split count
#define KTI 9      // inv K-tiles (288/32)
#define SCALE_V 0.022097086912079608f  // sqrt(2)/64
#define INV_S 45.25483399593904f       // 1/SCALE_V

typedef __attribute__((ext_vector_type(8))) short s8v;
typedef __attribute__((ext_vector_type(4))) float f4v;
typedef __attribute__((ext_vector_type(4))) unsigned u32x4;
typedef unsigned short u16;
typedef unsigned int u32;

#define MF(A, B, C) C = __builtin_amdgcn_mfma_f32_16x16x32_bf16(A, B, C, 0, 0, 0)

static __device__ __forceinline__ float gelu_f(float x) {
  return 0.5f * x * (1.0f + erff(x * 0.70710678118654752f));
}

// RNE split (used in k_mix / k_cw only — not hot)
static __device__ __forceinline__ void bsplit(float v, u16 &hi, u16 &lo) {
  __hip_bfloat16 h = __float2bfloat16(v);
  hi = __builtin_bit_cast(u16, h);
  float r = v - __bfloat162float(h);
  lo = __builtin_bit_cast(u16, __float2bfloat16(r));
}

// truncation split of a PAIR -> packed hi-word and lo-word (6 VALU)
static __device__ __forceinline__ void split2(float v0, float v1, u32 &hw, u32 &lw) {
  u32 b0 = __builtin_bit_cast(u32, v0) & 0xFFFF0000u;
  u32 b1 = __builtin_bit_cast(u32, v1) & 0xFFFF0000u;
  float r0 = v0 - __builtin_bit_cast(float, b0);
  float r1 = v1 - __builtin_bit_cast(float, b1);
  hw = __builtin_amdgcn_perm(b1, b0, 0x07060302u);
  lw = __builtin_amdgcn_perm(__builtin_bit_cast(u32, r1), __builtin_bit_cast(u32, r0), 0x07060302u);
}

// ---------------- min/max reduction ----------------
__global__ void k_minmax1(const float* __restrict__ pos, float* __restrict__ partials) {
  int t = threadIdx.x;
  float mnx = 1e30f, mxx = -1e30f, mny = 1e30f, mxy = -1e30f;
  for (int idx = blockIdx.x * 256 + t; idx < BB * NPT; idx += 64 * 256) {
    float2 p = ((const float2*)pos)[idx];
    mnx = fminf(mnx, p.x); mxx = fmaxf(mxx, p.x);
    mny = fminf(mny, p.y); mxy = fmaxf(mxy, p.y);
  }
  for (int o = 32; o > 0; o >>= 1) {
    mnx = fminf(mnx, __shfl_down(mnx, o));
    mxx = fmaxf(mxx, __shfl_down(mxx, o));
    mny = fminf(mny, __shfl_down(mny, o));
    mxy = fmaxf(mxy, __shfl_down(mxy, o));
  }
  __shared__ float sm[4][4];
  if ((t & 63) == 0) { int wv = t >> 6; sm[wv][0] = mnx; sm[wv][1] = mxx; sm[wv][2] = mny; sm[wv][3] = mxy; }
  __syncthreads();
  if (t == 0) {
    for (int w = 1; w < 4; ++w) {
      mnx = fminf(mnx, sm[w][0]); mxx = fmaxf(mxx, sm[w][1]);
      mny = fminf(mny, sm[w][2]); mxy = fmaxf(mxy, sm[w][3]);
    }
    partials[blockIdx.x * 4 + 0] = mnx; partials[blockIdx.x * 4 + 1] = mxx;
    partials[blockIdx.x * 4 + 2] = mny; partials[blockIdx.x * 4 + 3] = mxy;
  }
}

__global__ void k_minmax2(const float* __restrict__ partials, float* __restrict__ scal) {
  int t = threadIdx.x;  // 64
  float mnx = partials[t * 4 + 0], mxx = partials[t * 4 + 1];
  float mny = partials[t * 4 + 2], mxy = partials[t * 4 + 3];
  for (int o = 32; o > 0; o >>= 1) {
    mnx = fminf(mnx, __shfl_down(mnx, o));
    mxx = fmaxf(mxx, __shfl_down(mxx, o));
    mny = fminf(mny, __shfl_down(mny, o));
    mxy = fmaxf(mxy, __shfl_down(mxy, o));
  }
  if (t == 0) {
    scal[0] = mnx; scal[1] = mny;
    scal[2] = 6.28f / (mxx - mnx);
    scal[3] = 6.28f / (mxy - mny);
  }
}

// ---------------- setup: fc0 + interleaved phasor tables ----------------
__global__ __launch_bounds__(256) void k_setup(const float* __restrict__ pos,
    const float* __restrict__ fc0w, const float* __restrict__ fc0b,
    const float* __restrict__ scal,
    float2* __restrict__ ExI, float2* __restrict__ EyI, float* __restrict__ hA) {
  int p = blockIdx.x * 256 + threadIdx.x;  // 65536
  int b = p >> 12, n = p & (NPT - 1);
  float px = pos[2 * p], py = pos[2 * p + 1];
  float xp = px - scal[0], yp = py - scal[1];
  float xs = xp * scal[2], ys = yp * scal[3];
  #pragma unroll
  for (int c = 0; c < CH; ++c)
    hA[((b * CH + c) << 12) + n] = fmaf(xp, fc0w[c], fmaf(yp, fc0w[32 + c], fc0b[c]));
  float cx, sx_; sincosf(xs, &sx_, &cx);
  ExI[(b * MX + 0) * NPT + n] = make_float2(SCALE_V, 0.f);
  float pr = SCALE_V, pi = 0.f;
  for (int k = 1; k <= 12; ++k) {
    float nr = pr * cx + pi * sx_;
    float ni = pi * cx - pr * sx_;
    pr = nr; pi = ni;
    if (k < 12) {
      ExI[(b * MX + k) * NPT + n] = make_float2(pr, pi);
      ExI[(b * MX + 24 - k) * NPT + n] = make_float2(pr, -pi);
    } else {
      ExI[(b * MX + 12) * NPT + n] = make_float2(pr, -pi);  // kx = -12
    }
  }
  float cy, sy_; sincosf(ys, &sy_, &cy);
  EyI[(b * MYK + 0) * NPT + n] = make_float2(1.f, 0.f);
  float qr = 1.f, qi = 0.f;
  for (int k = 1; k <= 11; ++k) {
    float nr = qr * cy + qi * sy_;
    float ni = qi * cy - qr * sy_;
    qr = nr; qi = ni;
    EyI[(b * MYK + k) * NPT + n] = make_float2(qr, qi);
    EyI[(b * MYK + 23 - k) * NPT + n] = make_float2(qr, -qi);
  }
}

// ---------------- weight transpose: wt[l][f][i][o] ----------------
__global__ __launch_bounds__(256) void k_wt(const float* __restrict__ sw1r, const float* __restrict__ sw1i,
    const float* __restrict__ sw2r, const float* __restrict__ sw2i,
    float* __restrict__ wtr, float* __restrict__ wti) {
  int l = blockIdx.x >> 6, i = (blockIdx.x >> 1) & 31, a = blockIdx.x & 1;
  __shared__ float S[2][32][145];
  const float* src1 = (a ? sw1i : sw1r) + ((l * 32 + i) * 32) * 144;
  const float* src2 = (a ? sw2i : sw2r) + ((l * 32 + i) * 32) * 144;
  for (int e = threadIdx.x; e < 32 * 144; e += 256) {
    S[0][e / 144][e % 144] = src1[e];
    S[1][e / 144][e % 144] = src2[e];
  }
  __syncthreads();
  float* dstbuf = a ? wti : wtr;
  for (int f0 = 0; f0 < 288; f0 += 8) {
    int f = f0 + (threadIdx.x >> 5), o = threadIdx.x & 31;
    float v = (f < 144) ? S[0][o][f] : S[1][o][f - 144];
    dstbuf[((l * 288 + f) * 32 + i) * 32 + o] = v;
  }
}

// ---------------- conv weights -> pre-split bf16 B-fragments ----------------
__global__ void k_cw(const float* __restrict__ cw, u16* __restrict__ cwb) {
  int l = blockIdx.x, t = threadIdx.x;
  for (int idx = t; idx < 1024; idx += 256) {
    int ct = idx >> 9, rem = idx & 511, lane = rem >> 3, e = rem & 7;
    int o = ct * 16 + (lane & 15);
    int c2 = (lane >> 4) * 8 + e;
    float v = cw[l * 1024 + o * 32 + c2];
    u16 hi, lo; bsplit(v, hi, lo);
    cwb[((l * 2 + 0) * 2 + ct) * 512 + lane * 8 + e] = hi;
    cwb[((l * 2 + 1) * 2 + ct) * 512 + lane * 8 + e] = lo;
  }
}

// ---------------- forward NUDFT via MFMA (depth-2 prefetch) ----------------
__global__ __launch_bounds__(384) void k_fwd_m(const float* __restrict__ hin,
    const float2* __restrict__ ExI, const float2* __restrict__ EyI,
    float* __restrict__ xfr, float* __restrict__ xfi) {
  const int b = blockIdx.y, s = blockIdx.z;
  const int t = threadIdx.x, w = t >> 6, l = t & 63;
  const int mtile = blockIdx.x * 6 + w;          // 0..17
  const int lr = l & 15, lg = l >> 4;
  const int f_row = mtile * 16 + lr;
  const int mp = 23 * (f_row / 12) + (f_row % 12);
  const int irow = mp % 24, jrow = mp / 24;

  __shared__ float2 exs[MX][34];
  __shared__ float2 eys[MYK][34];
  __shared__ u16 bh[2][64][8];
  __shared__ u16 bl[2][64][8];

  f4v aR0 = {0.f,0.f,0.f,0.f}, aI0 = {0.f,0.f,0.f,0.f};
  f4v aR1 = {0.f,0.f,0.f,0.f}, aI1 = {0.f,0.f,0.f,0.f};
  const int nbase = s << 8;   // 256-wide K chunk

  const int rS = t >> 5, nS = t & 31;
  const int cA = t >> 4, nrA = (t & 15) * 2;
  const int cB = (t + 384) >> 4, nrB = ((t + 384) & 15) * 2;
  const int ctA = cA >> 4, lnA = ((nrA >> 3) << 4) | (cA & 15), eeA = nrA & 7;
  const int ctB = cB >> 4, lnB = ((nrB >> 3) << 4) | (cB & 15), eeB = nrB & 7;

  float2 apx0, apx1, apy0, apy1, ah2, ah3;
  float2 bpx0, bpx1, bpy0, bpy1, bh2, bh3;

#define PFL(kt, px0_, px1_, py0_, py1_, h2_, h3_) { \
    const int n0_ = nbase + ((kt) << 5); \
    px0_ = ExI[(b * MX + rS) * NPT + n0_ + nS]; \
    px1_ = ExI[(b * MX + rS + 12) * NPT + n0_ + nS]; \
    py0_ = EyI[(b * MYK + rS) * NPT + n0_ + nS]; \
    if (t < 352) py1_ = EyI[(b * MYK + rS + 12) * NPT + n0_ + nS]; \
    h2_ = *(const float2*)&hin[((b * CH + cA) << 12) + n0_ + nrA]; \
    if (t < 128) h3_ = *(const float2*)&hin[((b * CH + cB) << 12) + n0_ + nrB]; }

#define STG(px0_, px1_, py0_, py1_, h2_, h3_) { \
    exs[rS][nS] = px0_; exs[rS + 12][nS] = px1_; \
    eys[rS][nS] = py0_; if (t < 352) eys[rS + 12][nS] = py1_; \
    u32 hw_, lw_; split2(h2_.x, h2_.y, hw_, lw_); \
    *(u32*)&bh[ctA][lnA][eeA] = hw_; *(u32*)&bl[ctA][lnA][eeA] = lw_; \
    if (t < 128) { u32 hw2_, lw2_; split2(h3_.x, h3_.y, hw2_, lw2_); \
      *(u32*)&bh[ctB][lnB][eeB] = hw2_; *(u32*)&bl[ctB][lnB][eeB] = lw2_; } }

  auto COMPUTE = [&]() {
    u32x4 rh, rl, ih, il;
    #pragma unroll
    for (int e2 = 0; e2 < 4; ++e2) {
      float4 qx = *(const float4*)&exs[irow][lg * 8 + 2 * e2];
      float4 qy = *(const float4*)&eys[jrow][lg * 8 + 2 * e2];
      float vr0 = qx.x * qy.x - qx.y * qy.y;
      float vi0 = qx.x * qy.y + qx.y * qy.x;
      float vr1 = qx.z * qy.z - qx.w * qy.w;
      float vi1 = qx.z * qy.w + qx.w * qy.z;
      u32 w0, w1, w2, w3;
      split2(vr0, vr1, w0, w1);
      split2(vi0, vi1, w2, w3);
      rh[e2] = w0; rl[e2] = w1; ih[e2] = w2; il[e2] = w3;
    }
    s8v arh = __builtin_bit_cast(s8v, rh), arl = __builtin_bit_cast(s8v, rl);
    s8v aih = __builtin_bit_cast(s8v, ih), ail = __builtin_bit_cast(s8v, il);
    s8v b0h = *(const s8v*)(&bh[0][l][0]);
    s8v b0l = *(const s8v*)(&bl[0][l][0]);
    s8v b1h = *(const s8v*)(&bh[1][l][0]);
    s8v b1l = *(const s8v*)(&bl[1][l][0]);
    MF(arh, b0h, aR0); MF(arh, b0l, aR0); MF(arl, b0h, aR0);
    MF(aih, b0h, aI0); MF(aih, b0l, aI0); MF(ail, b0h, aI0);
    MF(arh, b1h, aR1); MF(arh, b1l, aR1); MF(arl, b1h, aR1);
    MF(aih, b1h, aI1); MF(aih, b1l, aI1); MF(ail, b1h, aI1);
  };

  PFL(0, apx0, apx1, apy0, apy1, ah2, ah3);
  PFL(1, bpx0, bpx1, bpy0, bpy1, bh2, bh3);
  #pragma unroll
  for (int kt2 = 0; kt2 < 4; ++kt2) {
    __syncthreads();
    STG(apx0, apx1, apy0, apy1, ah2, ah3);
    if (kt2 < 3) PFL(2 * kt2 + 2, apx0, apx1, apy0, apy1, ah2, ah3);
    __syncthreads();
    COMPUTE();
    __syncthreads();
    STG(bpx0, bpx1, bpy0, bpy1, bh2, bh3);
    if (kt2 < 3) PFL(2 * kt2 + 3, bpx0, bpx1, bpy0, bpy1, bh2, bh3);
    __syncthreads();
    COMPUTE();
  }
#undef PFL
#undef STG
  #pragma unroll
  for (int r = 0; r < 4; ++r) {
    int fo = mtile * 16 + lg * 4 + r;
    int base = ((s * BB + b) * NF + fo) * CH + lr;
    xfr[base] = aR0[r]; xfr[base + 16] = aR1[r];
    xfi[base] = aI0[r]; xfi[base + 16] = aI1[r];
  }
}

// ---------------- fullB store helper (pre-split bf16, inv B-fragment layout) ----------------
static __device__ __forceinline__ void fbs(u16* __restrict__ fb, int b, int f, int c, int ri, float v) {
  int kt = f >> 5, kr = f & 31;
  int ct = c >> 4, ln = ((kr >> 3) << 4) | (c & 15), e = kr & 7;
  u16 hi, lo; bsplit(v, hi, lo);
  int off = (b * KTI + kt) * 4096 + ri * 2048 + ct * 512 + ln * 8 + e;
  fb[off] = hi;
  fb[off + 1024] = lo;
}

// ---------------- mode mixing -> F ----------------
__global__ __launch_bounds__(256) void k_mix(const float* __restrict__ xfr, const float* __restrict__ xfi,
    const float* __restrict__ wtr, const float* __restrict__ wti,
    u16* __restrict__ fullB, int l) {
  const int f = blockIdx.x, b = blockIdx.y;
  const int t = threadIdx.x;
  __shared__ float xr_[CH], xi_[CH];
  __shared__ float rr[8][33], ri_[8][33];
  if (t < 64) {
    int i = t & 31, isIm = t >> 5;
    const float* src = isIm ? xfi : xfr;
    float v = 0.f;
    #pragma unroll
    for (int s = 0; s < NS; ++s) v += src[((s * BB + b) * NF + f) * CH + i];
    if (isIm) xi_[i] = v; else xr_[i] = v;
  }
  __syncthreads();
  {
    int o = t & 31, ig = t >> 5;
    float pr = 0.f, pi = 0.f;
    const float* wr_base = wtr + (l * NF + f) * CH * CH;
    const float* wi_base = wti + (l * NF + f) * CH * CH;
    #pragma unroll
    for (int q = 0; q < 4; ++q) {
      int i = ig * 4 + q;
      float xr = xr_[i], xi = xi_[i];
      float w1 = wr_base[i * CH + o], w2 = wi_base[i * CH + o];
      pr += xr * w1 - xi * w2;
      pi += xr * w2 + xi * w1;
    }
    rr[ig][o] = pr; ri_[ig][o] = pi;
  }
  __syncthreads();
  if (t < 64) {
    int o2 = t & 31, isIm = t >> 5;
    float v = 0.f;
    #pragma unroll
    for (int g = 0; g < 8; ++g) v += isIm ? ri_[g][o2] : rr[g][o2];
    fbs(fullB, b, f, o2, isIm, v);
  }
}

// ---------------- inverse NUDFT (K=288, rotation post-MFMA, barrier-free K-loop) ----------------
// All waves read identical F fragments -> load straight from global (L2-resident),
// no LDS staging, no barriers in the K-loop; waves free-run.
// P    = conv + sum_all (Vr Fr + Vi Fi)
// B2f  = sum_all (Vi Fr - Vr Fi)
// S1a  = conv + sum_{f<24}(Vr Fr + Vi Fi) ;  S1b = sum_{f<24}(Vi Fr - Vr Fi)
// out[n,c] = P[n,c] + [cos(xs)*(P-S1a) + sin(xs)*(B2f-S1b)][n,31-c] + cb
__global__ __launch_bounds__(256) void k_inv_m(const float* __restrict__ hin,
    const float2* __restrict__ ExI, const float2* __restrict__ EyI,
    const u16* __restrict__ fullB,
    const u16* __restrict__ cwb, const float* __restrict__ cb,
    float* __restrict__ hout, int l, int doGelu) {
  const int b = blockIdx.y;
  const int n0 = blockIdx.x << 6;
  const int t = threadIdx.x, w = t >> 6, l6 = t & 63;
  const int lr = l6 & 15, lg = l6 >> 4;

  __shared__ float2 exT[64][26];   // [n][i]

  const int nloc = w * 16 + lr;

  // stage exT (A-build rows + epilogue rotation factors)
  for (int e = t; e < MX * 64; e += 256) { int i = e >> 6, nn = e & 63; exT[nn][i] = ExI[(b * MX + i) * NPT + n0 + nn]; }

  // per-lane Ey registers: j is a function of (kt, lg) only
  float2 eyv[KTI];
  #pragma unroll
  for (int kt = 0; kt < KTI; ++kt) {
    int mb = (kt << 5) + (lg << 3);
    int j = (mb * 2731) >> 16;          // mb / 24, <= 11
    eyv[kt] = EyI[(b * MYK + j) * NPT + n0 + nloc];
  }

  // per-lane conv A-fragment: h[nloc][lg*8 + e] (direct gather, no LDS)
  s8v ah_c, al_c;
  {
    float hv[8];
    #pragma unroll
    for (int e = 0; e < 8; ++e)
      hv[e] = hin[((b * CH + lg * 8 + e) << 12) + n0 + nloc];
    u32x4 hh, hl2;
    #pragma unroll
    for (int e2 = 0; e2 < 4; ++e2) {
      u32 a_, b_;
      split2(hv[2 * e2], hv[2 * e2 + 1], a_, b_);
      hh[e2] = a_; hl2[e2] = b_;
    }
    ah_c = __builtin_bit_cast(s8v, hh);
    al_c = __builtin_bit_cast(s8v, hl2);
  }

  const u16* cwp = cwb + l * 2048;
  s8v cwh0 = *(const s8v*)(cwp + 0    + l6 * 8);
  s8v cwh1 = *(const s8v*)(cwp + 512  + l6 * 8);
  s8v cwl0 = *(const s8v*)(cwp + 1024 + l6 * 8);
  s8v cwl1 = *(const s8v*)(cwp + 1536 + l6 * 8);

  __syncthreads();   // exT ready; no further barriers

  f4v P0 = {0,0,0,0}, P1 = {0,0,0,0}, B0 = {0,0,0,0}, B1 = {0,0,0,0};
  // conv skip via MFMA into P (register-only), snapshot into S1a
  MF(ah_c, cwh0, P0); MF(ah_c, cwl0, P0); MF(al_c, cwh0, P0);
  MF(ah_c, cwh1, P1); MF(ah_c, cwl1, P1); MF(al_c, cwh1, P1);
  f4v S1a0 = P0, S1a1 = P1, S1b0 = {0,0,0,0}, S1b1 = {0,0,0,0};

  const u16* fbb = fullB + (size_t)(b * KTI) * 4096 + l6 * 8;

  #pragma unroll
  for (int kt = 0; kt < KTI; ++kt) {
    const u16* bp = fbb + kt * 4096;
    // F fragments straight from global (identical across waves, L2-resident)
    s8v Frh0 = *(const s8v*)(bp + 0);
    s8v Frh1 = *(const s8v*)(bp + 512);
    s8v Frl0 = *(const s8v*)(bp + 1024);
    s8v Frl1 = *(const s8v*)(bp + 1536);
    s8v Fih0 = *(const s8v*)(bp + 2048);
    s8v Fih1 = *(const s8v*)(bp + 2560);
    s8v Fil0 = *(const s8v*)(bp + 3072);
    s8v Fil1 = *(const s8v*)(bp + 3584);

    const int mbase = (kt << 5) + (lg << 3);
    const int j = (mbase * 2731) >> 16;
    const int i0 = mbase - 24 * j;
    const float2 ey = eyv[kt];
    u32x4 rh, rl, ih, il;
    #pragma unroll
    for (int e2 = 0; e2 < 4; ++e2) {
      float4 q = *(const float4*)&exT[nloc][i0 + 2 * e2];
      float vr0 = q.x * ey.x - q.y * ey.y;
      float vi0 = q.x * ey.y + q.y * ey.x;
      float vr1 = q.z * ey.x - q.w * ey.y;
      float vi1 = q.z * ey.y + q.w * ey.x;
      u32 w0, w1, w2, w3;
      split2(vr0, vr1, w0, w1);
      split2(vi0, vi1, w2, w3);
      rh[e2] = w0; rl[e2] = w1; ih[e2] = w2; il[e2] = w3;
    }
    s8v arh = __builtin_bit_cast(s8v, rh), arl = __builtin_bit_cast(s8v, rl);
    s8v aih = __builtin_bit_cast(s8v, ih), ail = __builtin_bit_cast(s8v, il);
    u32x4 nh = rh ^ 0x80008000u, nl2 = rl ^ 0x80008000u;
    s8v narh = __builtin_bit_cast(s8v, nh), narl = __builtin_bit_cast(s8v, nl2);

    // P += Vr*Fr + Vi*Fi
    MF(arh, Frh0, P0); MF(arh, Frl0, P0); MF(arl, Frh0, P0);
    MF(aih, Fih0, P0); MF(aih, Fil0, P0); MF(ail, Fih0, P0);
    MF(arh, Frh1, P1); MF(arh, Frl1, P1); MF(arl, Frh1, P1);
    MF(aih, Fih1, P1); MF(aih, Fil1, P1); MF(ail, Fih1, P1);
    // B2f += Vi*Fr - Vr*Fi
    MF(aih, Frh0, B0); MF(aih, Frl0, B0); MF(ail, Frh0, B0);
    MF(narh, Fih0, B0); MF(narh, Fil0, B0); MF(narl, Fih0, B0);
    MF(aih, Frh1, B1); MF(aih, Frl1, B1); MF(ail, Frh1, B1);
    MF(narh, Fih1, B1); MF(narh, Fil1, B1); MF(narl, Fih1, B1);
    if (kt == 0) {
      // S1 chains: f<24 = k-slots 0..23 -> lanes lg<3 live, lg==3 zeroed
      s8v z = {0,0,0,0,0,0,0,0};
      bool live = (lg < 3);
      s8v zrh = live ? arh : z, zrl = live ? arl : z;
      s8v zih = live ? aih : z, zil = live ? ail : z;
      s8v znrh = live ? narh : z, znrl = live ? narl : z;
      MF(zrh, Frh0, S1a0); MF(zrh, Frl0, S1a0); MF(zrl, Frh0, S1a0);
      MF(zih, Fih0, S1a0); MF(zih, Fil0, S1a0); MF(zil, Fih0, S1a0);
      MF(zrh, Frh1, S1a1); MF(zrh, Frl1, S1a1); MF(zrl, Frh1, S1a1);
      MF(zih, Fih1, S1a1); MF(zih, Fil1, S1a1); MF(zil, Fih1, S1a1);
      MF(zih, Frh0, S1b0); MF(zih, Frl0, S1b0); MF(zil, Frh0, S1b0);
      MF(znrh, Fih0, S1b0); MF(znrh, Fil0, S1b0); MF(znrl, Fih0, S1b0);
      MF(zih, Frh1, S1b1); MF(zih, Frl1, S1b1); MF(zil, Frh1, S1b1);
      MF(znrh, Fih1, S1b1); MF(znrh, Fil1, S1b1); MF(znrl, Fih1, S1b1);
    }
  }

  // epilogue: U = cos*A2 + sin*B2 at this lane's D-rows; flip channels via shfl
  float cb0 = cb[l * CH + lr];
  float cb1 = cb[l * CH + 16 + lr];
  #pragma unroll
  for (int r = 0; r < 4; ++r) {
    int nn = w * 16 + lg * 4 + r;
    float2 e1 = exT[nn][1];                 // SCALE * exp(-i*xs_nn)
    float cs = e1.x * INV_S, sn = -e1.y * INV_S;
    float a20 = P0[r] - S1a0[r], a21 = P1[r] - S1a1[r];
    float b20 = B0[r] - S1b0[r], b21 = B1[r] - S1b1[r];
    float U0r = cs * a20 + sn * b20;
    float U1r = cs * a21 + sn * b21;
    float u1s = __shfl_xor(U1r, 15, 64);
    float u0s = __shfl_xor(U0r, 15, 64);
    float v0 = P0[r] + u1s + cb0;
    float v1 = P1[r] + u0s + cb1;
    if (doGelu) { v0 = gelu_f(v0); v1 = gelu_f(v1); }
    hout[((b * CH + lr) << 12) + n0 + nn] = v0;
    hout[((b * CH + 16 + lr) << 12) + n0 + nn] = v1;
  }
}

// ---------------- final: fc1 + gelu + fc2 ----------------
__global__ __launch_bounds__(256) void k_final(const float* __restrict__ hin,
    const float* __restrict__ fc1w, const float* __restrict__ fc1b,
    const float* __restrict__ fc2w, const float* __restrict__ fc2b, float* __restrict__ out) {
  __shared__ float w1s[CH * 128];
  __shared__ float b1s[128], w2s[128];
  int t = threadIdx.x;
  for (int e = t; e < CH * 128; e += 256) w1s[e] = fc1w[e];
  if (t < 128) { b1s[t] = fc1b[t]; w2s[t] = fc2w[t]; }
  __syncthreads();
  int p = blockIdx.x * 256 + t;
  int b = p >> 12, n = p & (NPT - 1);
  float h[CH];
  #pragma unroll
  for (int c2 = 0; c2 < CH; ++c2) h[c2] = hin[((b * CH + c2) << 12) + n];
  float o = fc2b[0];
  for (int k0 = 0; k0 < 128; k0 += 4) {
    float4 a = *(const float4*)&b1s[k0];
    #pragma unroll
    for (int c2 = 0; c2 < CH; ++c2) {
      float4 wv = *(const float4*)&w1s[c2 * 128 + k0];
      a.x += h[c2] * wv.x; a.y += h[c2] * wv.y;
      a.z += h[c2] * wv.z; a.w += h[c2] * wv.w;
    }
    float4 g = *(const float4*)&w2s[k0];
    o += gelu_f(a.x) * g.x + gelu_f(a.y) * g.y + gelu_f(a.z) * g.z + gelu_f(a.w) * g.w;
  }
  out[p] = o;
}

extern "C" void kernel_launch(void* const* d_in, const int* in_sizes, int n_in,
                              void* d_out, int out_size, void* d_ws, size_t ws_size,
                              hipStream_t stream) {
  const float* pos   = (const float*)d_in[0];
  const float* fc0_w = (const float*)d_in[1];
  const float* fc0_b = (const float*)d_in[2];
  const float* sw1r  = (const float*)d_in[3];
  const float* sw1i  = (const float*)d_in[4];
  const float* sw2r  = (const float*)d_in[5];
  const float* sw2i  = (const float*)d_in[6];
  const float* cw    = (const float*)d_in[7];
  const float* cb    = (const float*)d_in[8];
  const float* fc1_w = (const float*)d_in[9];
  const float* fc1_b = (const float*)d_in[10];
  const float* fc2_w = (const float*)d_in[11];
  const float* fc2_b = (const float*)d_in[12];
  float* out = (float*)d_out;
  float* ws = (float*)d_ws;

  size_t off = 0;
  float* partials = ws;                 off += 256;
  float* scal = ws + off;               off += 16;
  float2* ExI = (float2*)(ws + off);    off += (size_t)BB * MX * NPT * 2;
  float2* EyI = (float2*)(ws + off);    off += (size_t)BB * MYK * NPT * 2;
  float* hA  = ws + off;                off += (size_t)BB * CH * NPT;
  float* hB  = ws + off;                off += (size_t)BB * CH * NPT;
  float* xfr = ws + off;                off += (size_t)NS * BB * NF * CH;
  float* xfi = ws + off;                off += (size_t)NS * BB * NF * CH;
  u16*  fullB = (u16*)(ws + off);       off += (size_t)BB * KTI * 4096 / 2;
  float* wtr = ws + off;                off += (size_t)4 * NF * CH * CH;
  float* wti = ws + off;                off += (size_t)4 * NF * CH * CH;
  u16*  cwb = (u16*)(ws + off);         off += 4096;
  // total ~17.2M floats (~69 MB)

  k_minmax1<<<64, 256, 0, stream>>>(pos, partials);
  k_minmax2<<<1, 64, 0, stream>>>(partials, scal);
  k_setup<<<(BB * NPT) / 256, 256, 0, stream>>>(pos, fc0_w, fc0_b, scal, ExI, EyI, hA);
  k_wt<<<256, 256, 0, stream>>>(sw1r, sw1i, sw2r, sw2i, wtr, wti);
  k_cw<<<4, 256, 0, stream>>>(cw, cwb);

  for (int l = 0; l < 4; ++l) {
    const float* hin = (l & 1) ? hB : hA;
    float* hout = (l & 1) ? hA : hB;
    k_fwd_m<<<dim3(3, BB, NS), 384, 0, stream>>>(hin, ExI, EyI, xfr, xfi);
    k_mix<<<dim3(NF, BB), 256, 0, stream>>>(xfr, xfi, wtr, wti, fullB, l);
    k_inv_m<<<dim3(64, BB), 256, 0, stream>>>(hin, ExI, EyI, fullB, cwb, cb,
                                              hout, l, (l < 3) ? 1 : 0);
  }
  k_final<<<(BB * NPT) / 256, 256, 0, stream>>>(hA, fc1_w, fc1_b, fc2_w, fc2_b, out);
}

// Round 10
// 284.448 us; speedup vs baseline: 1.0221x; 1.0221x over previous
//
#include <hip/hip_runtime.h>
#include <hip/hip_bf16.h>
#include <math.h>

#define BB 16
#define NPT 4096
#define CH 32
#define MX 24      // kx count
#define MYK 23     // ky count
#define NF 288
#define NS 16      // fwd K-split count
#define KTI 9      // inv K-tiles (288/32)
#define SCALE_V 0.022097086912079608f  // sqrt(2)/64
#define INV_S 45.25483399593904f       // 1/SCALE_V

typedef __attribute__((ext_vector_type(8))) short s8v;
typedef __attribute__((ext_vector_type(4))) float f4v;
typedef __attribute__((ext_vector_type(4))) unsigned u32x4;
typedef unsigned short u16;
typedef unsigned int u32;

#define MF(A, B, C) C = __builtin_amdgcn_mfma_f32_16x16x32_bf16(A, B, C, 0, 0, 0)

static __device__ __forceinline__ float gelu_f(float x) {
  return 0.5f * x * (1.0f + erff(x * 0.70710678118654752f));
}

// RNE split (used in k_mix / k_wtcw only — not hot)
static __device__ __forceinline__ void bsplit(float v, u16 &hi, u16 &lo) {
  __hip_bfloat16 h = __float2bfloat16(v);
  hi = __builtin_bit_cast(u16, h);
  float r = v - __bfloat162float(h);
  lo = __builtin_bit_cast(u16, __float2bfloat16(r));
}

// truncation split of a PAIR -> packed hi-word and lo-word (6 VALU)
static __device__ __forceinline__ void split2(float v0, float v1, u32 &hw, u32 &lw) {
  u32 b0 = __builtin_bit_cast(u32, v0) & 0xFFFF0000u;
  u32 b1 = __builtin_bit_cast(u32, v1) & 0xFFFF0000u;
  float r0 = v0 - __builtin_bit_cast(float, b0);
  float r1 = v1 - __builtin_bit_cast(float, b1);
  hw = __builtin_amdgcn_perm(b1, b0, 0x07060302u);
  lw = __builtin_amdgcn_perm(__builtin_bit_cast(u32, r1), __builtin_bit_cast(u32, r0), 0x07060302u);
}

// ---------------- min/max reduction ----------------
__global__ void k_minmax1(const float* __restrict__ pos, float* __restrict__ partials) {
  int t = threadIdx.x;
  float mnx = 1e30f, mxx = -1e30f, mny = 1e30f, mxy = -1e30f;
  for (int idx = blockIdx.x * 256 + t; idx < BB * NPT; idx += 64 * 256) {
    float2 p = ((const float2*)pos)[idx];
    mnx = fminf(mnx, p.x); mxx = fmaxf(mxx, p.x);
    mny = fminf(mny, p.y); mxy = fmaxf(mxy, p.y);
  }
  for (int o = 32; o > 0; o >>= 1) {
    mnx = fminf(mnx, __shfl_down(mnx, o));
    mxx = fmaxf(mxx, __shfl_down(mxx, o));
    mny = fminf(mny, __shfl_down(mny, o));
    mxy = fmaxf(mxy, __shfl_down(mxy, o));
  }
  __shared__ float sm[4][4];
  if ((t & 63) == 0) { int wv = t >> 6; sm[wv][0] = mnx; sm[wv][1] = mxx; sm[wv][2] = mny; sm[wv][3] = mxy; }
  __syncthreads();
  if (t == 0) {
    for (int w = 1; w < 4; ++w) {
      mnx = fminf(mnx, sm[w][0]); mxx = fmaxf(mxx, sm[w][1]);
      mny = fminf(mny, sm[w][2]); mxy = fmaxf(mxy, sm[w][3]);
    }
    partials[blockIdx.x * 4 + 0] = mnx; partials[blockIdx.x * 4 + 1] = mxx;
    partials[blockIdx.x * 4 + 2] = mny; partials[blockIdx.x * 4 + 3] = mxy;
  }
}

__global__ void k_minmax2(const float* __restrict__ partials, float* __restrict__ scal) {
  int t = threadIdx.x;  // 64
  float mnx = partials[t * 4 + 0], mxx = partials[t * 4 + 1];
  float mny = partials[t * 4 + 2], mxy = partials[t * 4 + 3];
  for (int o = 32; o > 0; o >>= 1) {
    mnx = fminf(mnx, __shfl_down(mnx, o));
    mxx = fmaxf(mxx, __shfl_down(mxx, o));
    mny = fminf(mny, __shfl_down(mny, o));
    mxy = fmaxf(mxy, __shfl_down(mxy, o));
  }
  if (t == 0) {
    scal[0] = mnx; scal[1] = mny;
    scal[2] = 6.28f / (mxx - mnx);
    scal[3] = 6.28f / (mxy - mny);
  }
}

// ---------------- setup: fc0 + interleaved phasor tables ----------------
__global__ __launch_bounds__(256) void k_setup(const float* __restrict__ pos,
    const float* __restrict__ fc0w, const float* __restrict__ fc0b,
    const float* __restrict__ scal,
    float2* __restrict__ ExI, float2* __restrict__ EyI, float* __restrict__ hA) {
  int p = blockIdx.x * 256 + threadIdx.x;  // 65536
  int b = p >> 12, n = p & (NPT - 1);
  float px = pos[2 * p], py = pos[2 * p + 1];
  float xp = px - scal[0], yp = py - scal[1];
  float xs = xp * scal[2], ys = yp * scal[3];
  #pragma unroll
  for (int c = 0; c < CH; ++c)
    hA[((b * CH + c) << 12) + n] = fmaf(xp, fc0w[c], fmaf(yp, fc0w[32 + c], fc0b[c]));
  float cx, sx_; sincosf(xs, &sx_, &cx);
  ExI[(b * MX + 0) * NPT + n] = make_float2(SCALE_V, 0.f);
  float pr = SCALE_V, pi = 0.f;
  for (int k = 1; k <= 12; ++k) {
    float nr = pr * cx + pi * sx_;
    float ni = pi * cx - pr * sx_;
    pr = nr; pi = ni;
    if (k < 12) {
      ExI[(b * MX + k) * NPT + n] = make_float2(pr, pi);
      ExI[(b * MX + 24 - k) * NPT + n] = make_float2(pr, -pi);
    } else {
      ExI[(b * MX + 12) * NPT + n] = make_float2(pr, -pi);  // kx = -12
    }
  }
  float cy, sy_; sincosf(ys, &sy_, &cy);
  EyI[(b * MYK + 0) * NPT + n] = make_float2(1.f, 0.f);
  float qr = 1.f, qi = 0.f;
  for (int k = 1; k <= 11; ++k) {
    float nr = qr * cy + qi * sy_;
    float ni = qi * cy - qr * sy_;
    qr = nr; qi = ni;
    EyI[(b * MYK + k) * NPT + n] = make_float2(qr, qi);
    EyI[(b * MYK + 23 - k) * NPT + n] = make_float2(qr, -qi);
  }
}

// ---------------- weight transpose + conv-weight fragments (merged) ----------------
__global__ __launch_bounds__(256) void k_wtcw(const float* __restrict__ sw1r, const float* __restrict__ sw1i,
    const float* __restrict__ sw2r, const float* __restrict__ sw2i,
    float* __restrict__ wtr, float* __restrict__ wti,
    const float* __restrict__ cw, u16* __restrict__ cwb) {
  if (blockIdx.x >= 256) {
    // conv weights -> pre-split bf16 B-fragments
    int l = blockIdx.x - 256, t = threadIdx.x;
    for (int idx = t; idx < 1024; idx += 256) {
      int ct = idx >> 9, rem = idx & 511, lane = rem >> 3, e = rem & 7;
      int o = ct * 16 + (lane & 15);
      int c2 = (lane >> 4) * 8 + e;
      float v = cw[l * 1024 + o * 32 + c2];
      u16 hi, lo; bsplit(v, hi, lo);
      cwb[((l * 2 + 0) * 2 + ct) * 512 + lane * 8 + e] = hi;
      cwb[((l * 2 + 1) * 2 + ct) * 512 + lane * 8 + e] = lo;
    }
    return;
  }
  int l = blockIdx.x >> 6, i = (blockIdx.x >> 1) & 31, a = blockIdx.x & 1;
  __shared__ float S[2][32][145];
  const float* src1 = (a ? sw1i : sw1r) + ((l * 32 + i) * 32) * 144;
  const float* src2 = (a ? sw2i : sw2r) + ((l * 32 + i) * 32) * 144;
  for (int e = threadIdx.x; e < 32 * 144; e += 256) {
    S[0][e / 144][e % 144] = src1[e];
    S[1][e / 144][e % 144] = src2[e];
  }
  __syncthreads();
  float* dstbuf = a ? wti : wtr;
  for (int f0 = 0; f0 < 288; f0 += 8) {
    int f = f0 + (threadIdx.x >> 5), o = threadIdx.x & 31;
    float v = (f < 144) ? S[0][o][f] : S[1][o][f - 144];
    dstbuf[((l * 288 + f) * 32 + i) * 32 + o] = v;
  }
}

// ---------------- forward NUDFT via MFMA (depth-2 prefetch; Ey per-lane from L1) ----------------
__global__ __launch_bounds__(384) void k_fwd_m(const float* __restrict__ hin,
    const float2* __restrict__ ExI, const float2* __restrict__ EyI,
    float* __restrict__ xfr, float* __restrict__ xfi) {
  const int b = blockIdx.y, s = blockIdx.z;
  const int t = threadIdx.x, w = t >> 6, l = t & 63;
  const int mtile = blockIdx.x * 6 + w;          // 0..17
  const int lr = l & 15, lg = l >> 4;
  const int f_row = mtile * 16 + lr;
  const int mp = 23 * (f_row / 12) + (f_row % 12);
  const int irow = mp % 24, jrow = mp / 24;

  __shared__ float2 exs[MX][34];
  __shared__ u16 bh[2][64][8];
  __shared__ u16 bl[2][64][8];

  f4v aR0 = {0.f,0.f,0.f,0.f}, aI0 = {0.f,0.f,0.f,0.f};
  f4v aR1 = {0.f,0.f,0.f,0.f}, aI1 = {0.f,0.f,0.f,0.f};
  const int nbase = s << 8;   // 256-wide K chunk

  // per-lane Ey row pointer (jrow is a lane constant): loads served by L1
  const float2* eyrow = EyI + ((size_t)(b * MYK + jrow)) * NPT + lg * 8;

  const int rS = t >> 5, nS = t & 31;   // rS 0..11 (Ex staging: 2 rows each)
  const int cA = t >> 4, nrA = (t & 15) * 2;
  const int cB = (t + 384) >> 4, nrB = ((t + 384) & 15) * 2;
  const int ctA = cA >> 4, lnA = ((nrA >> 3) << 4) | (cA & 15), eeA = nrA & 7;
  const int ctB = cB >> 4, lnB = ((nrB >> 3) << 4) | (cB & 15), eeB = nrB & 7;

  float2 apx0, apx1, ah2, ah3;
  float2 bpx0, bpx1, bh2, bh3;

#define PFL(kt, px0_, px1_, h2_, h3_) { \
    const int n0_ = nbase + ((kt) << 5); \
    px0_ = ExI[(b * MX + rS) * NPT + n0_ + nS]; \
    px1_ = ExI[(b * MX + rS + 12) * NPT + n0_ + nS]; \
    h2_ = *(const float2*)&hin[((b * CH + cA) << 12) + n0_ + nrA]; \
    if (t < 128) h3_ = *(const float2*)&hin[((b * CH + cB) << 12) + n0_ + nrB]; }

#define STG(px0_, px1_, h2_, h3_) { \
    exs[rS][nS] = px0_; exs[rS + 12][nS] = px1_; \
    u32 hw_, lw_; split2(h2_.x, h2_.y, hw_, lw_); \
    *(u32*)&bh[ctA][lnA][eeA] = hw_; *(u32*)&bl[ctA][lnA][eeA] = lw_; \
    if (t < 128) { u32 hw2_, lw2_; split2(h3_.x, h3_.y, hw2_, lw2_); \
      *(u32*)&bh[ctB][lnB][eeB] = hw2_; *(u32*)&bl[ctB][lnB][eeB] = lw2_; } }

  auto COMPUTE = [&](int n0_) {
    u32x4 rh, rl, ih, il;
    #pragma unroll
    for (int e2 = 0; e2 < 4; ++e2) {
      float4 qx = *(const float4*)&exs[irow][lg * 8 + 2 * e2];
      float4 qy = *(const float4*)&eyrow[n0_ + 2 * e2];
      float vr0 = qx.x * qy.x - qx.y * qy.y;
      float vi0 = qx.x * qy.y + qx.y * qy.x;
      float vr1 = qx.z * qy.z - qx.w * qy.w;
      float vi1 = qx.z * qy.w + qx.w * qy.z;
      u32 w0, w1, w2, w3;
      split2(vr0, vr1, w0, w1);
      split2(vi0, vi1, w2, w3);
      rh[e2] = w0; rl[e2] = w1; ih[e2] = w2; il[e2] = w3;
    }
    s8v arh = __builtin_bit_cast(s8v, rh), arl = __builtin_bit_cast(s8v, rl);
    s8v aih = __builtin_bit_cast(s8v, ih), ail = __builtin_bit_cast(s8v, il);
    s8v b0h = *(const s8v*)(&bh[0][l][0]);
    s8v b0l = *(const s8v*)(&bl[0][l][0]);
    s8v b1h = *(const s8v*)(&bh[1][l][0]);
    s8v b1l = *(const s8v*)(&bl[1][l][0]);
    MF(arh, b0h, aR0); MF(arh, b0l, aR0); MF(arl, b0h, aR0);
    MF(aih, b0h, aI0); MF(aih, b0l, aI0); MF(ail, b0h, aI0);
    MF(arh, b1h, aR1); MF(arh, b1l, aR1); MF(arl, b1h, aR1);
    MF(aih, b1h, aI1); MF(aih, b1l, aI1); MF(ail, b1h, aI1);
  };

  PFL(0, apx0, apx1, ah2, ah3);
  PFL(1, bpx0, bpx1, bh2, bh3);
  #pragma unroll
  for (int kt2 = 0; kt2 < 4; ++kt2) {
    __syncthreads();
    STG(apx0, apx1, ah2, ah3);
    if (kt2 < 3) PFL(2 * kt2 + 2, apx0, apx1, ah2, ah3);
    __syncthreads();
    COMPUTE(nbase + ((2 * kt2) << 5));
    __syncthreads();
    STG(bpx0, bpx1, bh2, bh3);
    if (kt2 < 3) PFL(2 * kt2 + 3, bpx0, bpx1, bh2, bh3);
    __syncthreads();
    COMPUTE(nbase + ((2 * kt2 + 1) << 5));
  }
#undef PFL
#undef STG
  #pragma unroll
  for (int r = 0; r < 4; ++r) {
    int fo = mtile * 16 + lg * 4 + r;
    int base = ((s * BB + b) * NF + fo) * CH + lr;
    xfr[base] = aR0[r]; xfr[base + 16] = aR1[r];
    xfi[base] = aI0[r]; xfi[base + 16] = aI1[r];
  }
}

// ---------------- fullB store helper (pre-split bf16, inv B-fragment layout) ----------------
static __device__ __forceinline__ void fbs(u16* __restrict__ fb, int b, int f, int c, int ri, float v) {
  int kt = f >> 5, kr = f & 31;
  int ct = c >> 4, ln = ((kr >> 3) << 4) | (c & 15), e = kr & 7;
  u16 hi, lo; bsplit(v, hi, lo);
  int off = (b * KTI + kt) * 4096 + ri * 2048 + ct * 512 + ln * 8 + e;
  fb[off] = hi;
  fb[off + 1024] = lo;
}

// ---------------- mode mixing -> F ----------------
__global__ __launch_bounds__(256) void k_mix(const float* __restrict__ xfr, const float* __restrict__ xfi,
    const float* __restrict__ wtr, const float* __restrict__ wti,
    u16* __restrict__ fullB, int l) {
  const int f = blockIdx.x, b = blockIdx.y;
  const int t = threadIdx.x;
  __shared__ float xr_[CH], xi_[CH];
  __shared__ float rr[8][33], ri_[8][33];
  if (t < 64) {
    int i = t & 31, isIm = t >> 5;
    const float* src = isIm ? xfi : xfr;
    float v = 0.f;
    #pragma unroll
    for (int s = 0; s < NS; ++s) v += src[((s * BB + b) * NF + f) * CH + i];
    if (isIm) xi_[i] = v; else xr_[i] = v;
  }
  __syncthreads();
  {
    int o = t & 31, ig = t >> 5;
    float pr = 0.f, pi = 0.f;
    const float* wr_base = wtr + (l * NF + f) * CH * CH;
    const float* wi_base = wti + (l * NF + f) * CH * CH;
    #pragma unroll
    for (int q = 0; q < 4; ++q) {
      int i = ig * 4 + q;
      float xr = xr_[i], xi = xi_[i];
      float w1 = wr_base[i * CH + o], w2 = wi_base[i * CH + o];
      pr += xr * w1 - xi * w2;
      pi += xr * w2 + xi * w1;
    }
    rr[ig][o] = pr; ri_[ig][o] = pi;
  }
  __syncthreads();
  if (t < 64) {
    int o2 = t & 31, isIm = t >> 5;
    float v = 0.f;
    #pragma unroll
    for (int g = 0; g < 8; ++g) v += isIm ? ri_[g][o2] : rr[g][o2];
    fbs(fullB, b, f, o2, isIm, v);
  }
}

// ---------------- inverse NUDFT (K=288, rotation post-MFMA, slim LDS — r8 best) ----------------
__global__ __launch_bounds__(256) void k_inv_m(const float* __restrict__ hin,
    const float2* __restrict__ ExI, const float2* __restrict__ EyI,
    const u16* __restrict__ fullB,
    const u16* __restrict__ cwb, const float* __restrict__ cb,
    float* __restrict__ hout, int l, int doGelu) {
  const int b = blockIdx.y;
  const int n0 = blockIdx.x << 6;
  const int t = threadIdx.x, w = t >> 6, l6 = t & 63;
  const int lr = l6 & 15, lg = l6 >> 4;

  __shared__ float2 exT[64][26];   // [n][i]
  __shared__ u16 bfr[4096];        // F tile (single buffer)

  const int nloc = w * 16 + lr;

  uint4 qa0, qa1, qb0, qb1;
#define LDNA(kt) { const uint4* s_ = (const uint4*)(fullB + (size_t)(b * KTI + (kt)) * 4096); qa0 = s_[t]; qa1 = s_[t + 256]; }
#define LDNB(kt) { const uint4* s_ = (const uint4*)(fullB + (size_t)(b * KTI + (kt)) * 4096); qb0 = s_[t]; qb1 = s_[t + 256]; }
#define WRTA { uint4* d_ = (uint4*)bfr; d_[t] = qa0; d_[t + 256] = qa1; }
#define WRTB { uint4* d_ = (uint4*)bfr; d_[t] = qb0; d_[t + 256] = qb1; }
  LDNA(0); LDNB(1);

  for (int e = t; e < MX * 64; e += 256) { int i = e >> 6, nn = e & 63; exT[nn][i] = ExI[(b * MX + i) * NPT + n0 + nn]; }

  // per-lane Ey registers: j is a function of (kt, lg) only
  float2 eyv[KTI];
  #pragma unroll
  for (int kt = 0; kt < KTI; ++kt) {
    int mb = (kt << 5) + (lg << 3);
    int j = (mb * 2731) >> 16;          // mb / 24, <= 11
    eyv[kt] = EyI[(b * MYK + j) * NPT + n0 + nloc];
  }

  // per-lane conv A-fragment: h[nloc][lg*8 + e] (direct gather, no LDS)
  s8v ah_c, al_c;
  {
    float hv[8];
    #pragma unroll
    for (int e = 0; e < 8; ++e)
      hv[e] = hin[((b * CH + lg * 8 + e) << 12) + n0 + nloc];
    u32x4 hh, hl2;
    #pragma unroll
    for (int e2 = 0; e2 < 4; ++e2) {
      u32 a_, b_;
      split2(hv[2 * e2], hv[2 * e2 + 1], a_, b_);
      hh[e2] = a_; hl2[e2] = b_;
    }
    ah_c = __builtin_bit_cast(s8v, hh);
    al_c = __builtin_bit_cast(s8v, hl2);
  }

  const u16* cwp = cwb + l * 2048;
  s8v cwh0 = *(const s8v*)(cwp + 0    + l6 * 8);
  s8v cwh1 = *(const s8v*)(cwp + 512  + l6 * 8);
  s8v cwl0 = *(const s8v*)(cwp + 1024 + l6 * 8);
  s8v cwl1 = *(const s8v*)(cwp + 1536 + l6 * 8);

  f4v P0 = {0,0,0,0}, P1 = {0,0,0,0}, B0 = {0,0,0,0}, B1 = {0,0,0,0};
  MF(ah_c, cwh0, P0); MF(ah_c, cwl0, P0); MF(al_c, cwh0, P0);
  MF(ah_c, cwh1, P1); MF(ah_c, cwl1, P1); MF(al_c, cwh1, P1);
  f4v S1a0 = P0, S1a1 = P1, S1b0 = {0,0,0,0}, S1b1 = {0,0,0,0};

  auto CMP = [&](int kt) {
    const int mbase = (kt << 5) + (lg << 3);
    const int j = (mbase * 2731) >> 16;
    const int i0 = mbase - 24 * j;
    const float2 ey = eyv[kt];
    u32x4 rh, rl, ih, il;
    #pragma unroll
    for (int e2 = 0; e2 < 4; ++e2) {
      float4 q = *(const float4*)&exT[nloc][i0 + 2 * e2];
      float vr0 = q.x * ey.x - q.y * ey.y;
      float vi0 = q.x * ey.y + q.y * ey.x;
      float vr1 = q.z * ey.x - q.w * ey.y;
      float vi1 = q.z * ey.y + q.w * ey.x;
      u32 w0, w1, w2, w3;
      split2(vr0, vr1, w0, w1);
      split2(vi0, vi1, w2, w3);
      rh[e2] = w0; rl[e2] = w1; ih[e2] = w2; il[e2] = w3;
    }
    s8v arh = __builtin_bit_cast(s8v, rh), arl = __builtin_bit_cast(s8v, rl);
    s8v aih = __builtin_bit_cast(s8v, ih), ail = __builtin_bit_cast(s8v, il);
    u32x4 nh = rh ^ 0x80008000u, nl2 = rl ^ 0x80008000u;
    s8v narh = __builtin_bit_cast(s8v, nh), narl = __builtin_bit_cast(s8v, nl2);

    const u16* bp = bfr;
    s8v Frh0 = *(const s8v*)(bp + 0    + l6 * 8);
    s8v Frh1 = *(const s8v*)(bp + 512  + l6 * 8);
    s8v Frl0 = *(const s8v*)(bp + 1024 + l6 * 8);
    s8v Frl1 = *(const s8v*)(bp + 1536 + l6 * 8);
    s8v Fih0 = *(const s8v*)(bp + 2048 + l6 * 8);
    s8v Fih1 = *(const s8v*)(bp + 2560 + l6 * 8);
    s8v Fil0 = *(const s8v*)(bp + 3072 + l6 * 8);
    s8v Fil1 = *(const s8v*)(bp + 3584 + l6 * 8);
    MF(arh, Frh0, P0); MF(arh, Frl0, P0); MF(arl, Frh0, P0);
    MF(aih, Fih0, P0); MF(aih, Fil0, P0); MF(ail, Fih0, P0);
    MF(arh, Frh1, P1); MF(arh, Frl1, P1); MF(arl, Frh1, P1);
    MF(aih, Fih1, P1); MF(aih, Fil1, P1); MF(ail, Fih1, P1);
    MF(aih, Frh0, B0); MF(aih, Frl0, B0); MF(ail, Frh0, B0);
    MF(narh, Fih0, B0); MF(narh, Fil0, B0); MF(narl, Fih0, B0);
    MF(aih, Frh1, B1); MF(aih, Frl1, B1); MF(ail, Frh1, B1);
    MF(narh, Fih1, B1); MF(narh, Fil1, B1); MF(narl, Fih1, B1);
    if (kt == 0) {
      s8v z = {0,0,0,0,0,0,0,0};
      bool live = (lg < 3);
      s8v zrh = live ? arh : z, zrl = live ? arl : z;
      s8v zih = live ? aih : z, zil = live ? ail : z;
      s8v znrh = live ? narh : z, znrl = live ? narl : z;
      MF(zrh, Frh0, S1a0); MF(zrh, Frl0, S1a0); MF(zrl, Frh0, S1a0);
      MF(zih, Fih0, S1a0); MF(zih, Fil0, S1a0); MF(zil, Fih0, S1a0);
      MF(zrh, Frh1, S1a1); MF(zrh, Frl1, S1a1); MF(zrl, Frh1, S1a1);
      MF(zih, Fih1, S1a1); MF(zih, Fil1, S1a1); MF(zil, Fih1, S1a1);
      MF(zih, Frh0, S1b0); MF(zih, Frl0, S1b0); MF(zil, Frh0, S1b0);
      MF(znrh, Fih0, S1b0); MF(znrh, Fil0, S1b0); MF(znrl, Fih0, S1b0);
      MF(zih, Frh1, S1b1); MF(zih, Frl1, S1b1); MF(zil, Frh1, S1b1);
      MF(znrh, Fih1, S1b1); MF(znrh, Fil1, S1b1); MF(znrl, Fih1, S1b1);
    }
  };

  #pragma unroll
  for (int kt2 = 0; kt2 < 4; ++kt2) {
    __syncthreads(); WRTA; LDNA(2 * kt2 + 2);
    __syncthreads(); CMP(2 * kt2);
    __syncthreads(); WRTB; if (kt2 < 3) LDNB(2 * kt2 + 3);
    __syncthreads(); CMP(2 * kt2 + 1);
  }
  __syncthreads(); WRTA;
  __syncthreads(); CMP(8);
#undef LDNA
#undef LDNB
#undef WRTA
#undef WRTB

  float cb0 = cb[l * CH + lr];
  float cb1 = cb[l * CH + 16 + lr];
  #pragma unroll
  for (int r = 0; r < 4; ++r) {
    int nn = w * 16 + lg * 4 + r;
    float2 e1 = exT[nn][1];                 // SCALE * exp(-i*xs_nn)
    float cs = e1.x * INV_S, sn = -e1.y * INV_S;
    float a20 = P0[r] - S1a0[r], a21 = P1[r] - S1a1[r];
    float b20 = B0[r] - S1b0[r], b21 = B1[r] - S1b1[r];
    float U0r = cs * a20 + sn * b20;
    float U1r = cs * a21 + sn * b21;
    float u1s = __shfl_xor(U1r, 15, 64);
    float u0s = __shfl_xor(U0r, 15, 64);
    float v0 = P0[r] + u1s + cb0;
    float v1 = P1[r] + u0s + cb1;
    if (doGelu) { v0 = gelu_f(v0); v1 = gelu_f(v1); }
    hout[((b * CH + lr) << 12) + n0 + nn] = v0;
    hout[((b * CH + 16 + lr) << 12) + n0 + nn] = v1;
  }
}

// ---------------- final: fc1 + gelu + fc2 ----------------
__global__ __launch_bounds__(256) void k_final(const float* __restrict__ hin,
    const float* __restrict__ fc1w, const float* __restrict__ fc1b,
    const float* __restrict__ fc2w, const float* __restrict__ fc2b, float* __restrict__ out) {
  __shared__ float w1s[CH * 128];
  __shared__ float b1s[128], w2s[128];
  int t = threadIdx.x;
  for (int e = t; e < CH * 128; e += 256) w1s[e] = fc1w[e];
  if (t < 128) { b1s[t] = fc1b[t]; w2s[t] = fc2w[t]; }
  __syncthreads();
  int p = blockIdx.x * 256 + t;
  int b = p >> 12, n = p & (NPT - 1);
  float h[CH];
  #pragma unroll
  for (int c2 = 0; c2 < CH; ++c2) h[c2] = hin[((b * CH + c2) << 12) + n];
  float o = fc2b[0];
  for (int k0 = 0; k0 < 128; k0 += 4) {
    float4 a = *(const float4*)&b1s[k0];
    #pragma unroll
    for (int c2 = 0; c2 < CH; ++c2) {
      float4 wv = *(const float4*)&w1s[c2 * 128 + k0];
      a.x += h[c2] * wv.x; a.y += h[c2] * wv.y;
      a.z += h[c2] * wv.z; a.w += h[c2] * wv.w;
    }
    float4 g = *(const float4*)&w2s[k0];
    o += gelu_f(a.x) * g.x + gelu_f(a.y) * g.y + gelu_f(a.z) * g.z + gelu_f(a.w) * g.w;
  }
  out[p] = o;
}

extern "C" void kernel_launch(void* const* d_in, const int* in_sizes, int n_in,
                              void* d_out, int out_size, void* d_ws, size_t ws_size,
                              hipStream_t stream) {
  const float* pos   = (const float*)d_in[0];
  const float* fc0_w = (const float*)d_in[1];
  const float* fc0_b = (const float*)d_in[2];
  const float* sw1r  = (const float*)d_in[3];
  const float* sw1i  = (const float*)d_in[4];
  const float* sw2r  = (const float*)d_in[5];
  const float* sw2i  = (const float*)d_in[6];
  const float* cw    = (const float*)d_in[7];
  const float* cb    = (const float*)d_in[8];
  const float* fc1_w = (const float*)d_in[9];
  const float* fc1_b = (const float*)d_in[10];
  const float* fc2_w = (const float*)d_in[11];
  const float* fc2_b = (const float*)d_in[12];
  float* out = (float*)d_out;
  float* ws = (float*)d_ws;

  size_t off = 0;
  float* partials = ws;                 off += 256;
  float* scal = ws + off;               off += 16;
  float2* ExI = (float2*)(ws + off);    off += (size_t)BB * MX * NPT * 2;
  float2* EyI = (float2*)(ws + off);    off += (size_t)BB * MYK * NPT * 2;
  float* hA  = ws + off;                off += (size_t)BB * CH * NPT;
  float* hB  = ws + off;                off += (size_t)BB * CH * NPT;
  float* xfr = ws + off;                off += (size_t)NS * BB * NF * CH;
  float* xfi = ws + off;                off += (size_t)NS * BB * NF * CH;
  u16*  fullB = (u16*)(ws + off);       off += (size_t)BB * KTI * 4096 / 2;
  float* wtr = ws + off;                off += (size_t)4 * NF * CH * CH;
  float* wti = ws + off;                off += (size_t)4 * NF * CH * CH;
  u16*  cwb = (u16*)(ws + off);         off += 4096;
  // total ~17.2M floats (~69 MB)

  k_minmax1<<<64, 256, 0, stream>>>(pos, partials);
  k_minmax2<<<1, 64, 0, stream>>>(partials, scal);
  k_setup<<<(BB * NPT) / 256, 256, 0, stream>>>(pos, fc0_w, fc0_b, scal, ExI, EyI, hA);
  k_wtcw<<<260, 256, 0, stream>>>(sw1r, sw1i, sw2r, sw2i, wtr, wti, cw, cwb);

  for (int l = 0; l < 4; ++l) {
    const float* hin = (l & 1) ? hB : hA;
    float* hout = (l & 1) ? hA : hB;
    k_fwd_m<<<dim3(3, BB, NS), 384, 0, stream>>>(hin, ExI, EyI, xfr, xfi);
    k_mix<<<dim3(NF, BB), 256, 0, stream>>>(xfr, xfi, wtr, wti, fullB, l);
    k_inv_m<<<dim3(64, BB), 256, 0, stream>>>(hin, ExI, EyI, fullB, cwb, cb,
                                              hout, l, (l < 3) ? 1 : 0);
  }
  k_final<<<(BB * NPT) / 256, 256, 0, stream>>>(hA, fc1_w, fc1_b, fc2_w, fc2_b, out);
}

// Round 11
// 283.269 us; speedup vs baseline: 1.0263x; 1.0042x over previous
//
#include <hip/hip_runtime.h>
#include <hip/hip_bf16.h>
#include <math.h>

#define BB 16
#define NPT 4096
#define CH 32
#define MX 24      // kx count
#define MYK 23     // ky count
#define NF 288
#define NS 16      // fwd K-split count
#define KTI 9      // inv K-tiles (288/32)
#define SCALE_V 0.022097086912079608f  // sqrt(2)/64
#define INV_S 45.25483399593904f       // 1/SCALE_V

typedef __attribute__((ext_vector_type(8))) short s8v;
typedef __attribute__((ext_vector_type(4))) float f4v;
typedef __attribute__((ext_vector_type(4))) unsigned u32x4;
typedef unsigned short u16;
typedef unsigned int u32;

#define MF(A, B, C) C = __builtin_amdgcn_mfma_f32_16x16x32_bf16(A, B, C, 0, 0, 0)

static __device__ __forceinline__ float gelu_f(float x) {
  return 0.5f * x * (1.0f + erff(x * 0.70710678118654752f));
}

// RNE split (used in k_mix / k_wtcw only — not hot)
static __device__ __forceinline__ void bsplit(float v, u16 &hi, u16 &lo) {
  __hip_bfloat16 h = __float2bfloat16(v);
  hi = __builtin_bit_cast(u16, h);
  float r = v - __bfloat162float(h);
  lo = __builtin_bit_cast(u16, __float2bfloat16(r));
}

// truncation split of a PAIR -> packed hi-word and lo-word (6 VALU)
static __device__ __forceinline__ void split2(float v0, float v1, u32 &hw, u32 &lw) {
  u32 b0 = __builtin_bit_cast(u32, v0) & 0xFFFF0000u;
  u32 b1 = __builtin_bit_cast(u32, v1) & 0xFFFF0000u;
  float r0 = v0 - __builtin_bit_cast(float, b0);
  float r1 = v1 - __builtin_bit_cast(float, b1);
  hw = __builtin_amdgcn_perm(b1, b0, 0x07060302u);
  lw = __builtin_amdgcn_perm(__builtin_bit_cast(u32, r1), __builtin_bit_cast(u32, r0), 0x07060302u);
}

// ---------------- min/max reduction ----------------
__global__ void k_minmax1(const float* __restrict__ pos, float* __restrict__ partials) {
  int t = threadIdx.x;
  float mnx = 1e30f, mxx = -1e30f, mny = 1e30f, mxy = -1e30f;
  for (int idx = blockIdx.x * 256 + t; idx < BB * NPT; idx += 64 * 256) {
    float2 p = ((const float2*)pos)[idx];
    mnx = fminf(mnx, p.x); mxx = fmaxf(mxx, p.x);
    mny = fminf(mny, p.y); mxy = fmaxf(mxy, p.y);
  }
  for (int o = 32; o > 0; o >>= 1) {
    mnx = fminf(mnx, __shfl_down(mnx, o));
    mxx = fmaxf(mxx, __shfl_down(mxx, o));
    mny = fminf(mny, __shfl_down(mny, o));
    mxy = fmaxf(mxy, __shfl_down(mxy, o));
  }
  __shared__ float sm[4][4];
  if ((t & 63) == 0) { int wv = t >> 6; sm[wv][0] = mnx; sm[wv][1] = mxx; sm[wv][2] = mny; sm[wv][3] = mxy; }
  __syncthreads();
  if (t == 0) {
    for (int w = 1; w < 4; ++w) {
      mnx = fminf(mnx, sm[w][0]); mxx = fmaxf(mxx, sm[w][1]);
      mny = fminf(mny, sm[w][2]); mxy = fmaxf(mxy, sm[w][3]);
    }
    partials[blockIdx.x * 4 + 0] = mnx; partials[blockIdx.x * 4 + 1] = mxx;
    partials[blockIdx.x * 4 + 2] = mny; partials[blockIdx.x * 4 + 3] = mxy;
  }
}

__global__ void k_minmax2(const float* __restrict__ partials, float* __restrict__ scal) {
  int t = threadIdx.x;  // 64
  float mnx = partials[t * 4 + 0], mxx = partials[t * 4 + 1];
  float mny = partials[t * 4 + 2], mxy = partials[t * 4 + 3];
  for (int o = 32; o > 0; o >>= 1) {
    mnx = fminf(mnx, __shfl_down(mnx, o));
    mxx = fmaxf(mxx, __shfl_down(mxx, o));
    mny = fminf(mny, __shfl_down(mny, o));
    mxy = fmaxf(mxy, __shfl_down(mxy, o));
  }
  if (t == 0) {
    scal[0] = mnx; scal[1] = mny;
    scal[2] = 6.28f / (mxx - mnx);
    scal[3] = 6.28f / (mxy - mny);
  }
}

// ---------------- setup: fc0 + interleaved phasor tables ----------------
__global__ __launch_bounds__(256) void k_setup(const float* __restrict__ pos,
    const float* __restrict__ fc0w, const float* __restrict__ fc0b,
    const float* __restrict__ scal,
    float2* __restrict__ ExI, float2* __restrict__ EyI, float* __restrict__ hA) {
  int p = blockIdx.x * 256 + threadIdx.x;  // 65536
  int b = p >> 12, n = p & (NPT - 1);
  float px = pos[2 * p], py = pos[2 * p + 1];
  float xp = px - scal[0], yp = py - scal[1];
  float xs = xp * scal[2], ys = yp * scal[3];
  #pragma unroll
  for (int c = 0; c < CH; ++c)
    hA[((b * CH + c) << 12) + n] = fmaf(xp, fc0w[c], fmaf(yp, fc0w[32 + c], fc0b[c]));
  float cx, sx_; sincosf(xs, &sx_, &cx);
  ExI[(b * MX + 0) * NPT + n] = make_float2(SCALE_V, 0.f);
  float pr = SCALE_V, pi = 0.f;
  for (int k = 1; k <= 12; ++k) {
    float nr = pr * cx + pi * sx_;
    float ni = pi * cx - pr * sx_;
    pr = nr; pi = ni;
    if (k < 12) {
      ExI[(b * MX + k) * NPT + n] = make_float2(pr, pi);
      ExI[(b * MX + 24 - k) * NPT + n] = make_float2(pr, -pi);
    } else {
      ExI[(b * MX + 12) * NPT + n] = make_float2(pr, -pi);  // kx = -12
    }
  }
  float cy, sy_; sincosf(ys, &sy_, &cy);
  EyI[(b * MYK + 0) * NPT + n] = make_float2(1.f, 0.f);
  float qr = 1.f, qi = 0.f;
  for (int k = 1; k <= 11; ++k) {
    float nr = qr * cy + qi * sy_;
    float ni = qi * cy - qr * sy_;
    qr = nr; qi = ni;
    EyI[(b * MYK + k) * NPT + n] = make_float2(qr, qi);
    EyI[(b * MYK + 23 - k) * NPT + n] = make_float2(qr, -qi);
  }
}

// ---------------- weight transpose + conv-weight fragments (merged) ----------------
__global__ __launch_bounds__(256) void k_wtcw(const float* __restrict__ sw1r, const float* __restrict__ sw1i,
    const float* __restrict__ sw2r, const float* __restrict__ sw2i,
    float* __restrict__ wtr, float* __restrict__ wti,
    const float* __restrict__ cw, u16* __restrict__ cwb) {
  if (blockIdx.x >= 256) {
    int l = blockIdx.x - 256, t = threadIdx.x;
    for (int idx = t; idx < 1024; idx += 256) {
      int ct = idx >> 9, rem = idx & 511, lane = rem >> 3, e = rem & 7;
      int o = ct * 16 + (lane & 15);
      int c2 = (lane >> 4) * 8 + e;
      float v = cw[l * 1024 + o * 32 + c2];
      u16 hi, lo; bsplit(v, hi, lo);
      cwb[((l * 2 + 0) * 2 + ct) * 512 + lane * 8 + e] = hi;
      cwb[((l * 2 + 1) * 2 + ct) * 512 + lane * 8 + e] = lo;
    }
    return;
  }
  int l = blockIdx.x >> 6, i = (blockIdx.x >> 1) & 31, a = blockIdx.x & 1;
  __shared__ float S[2][32][145];
  const float* src1 = (a ? sw1i : sw1r) + ((l * 32 + i) * 32) * 144;
  const float* src2 = (a ? sw2i : sw2r) + ((l * 32 + i) * 32) * 144;
  for (int e = threadIdx.x; e < 32 * 144; e += 256) {
    S[0][e / 144][e % 144] = src1[e];
    S[1][e / 144][e % 144] = src2[e];
  }
  __syncthreads();
  float* dstbuf = a ? wti : wtr;
  for (int f0 = 0; f0 < 288; f0 += 8) {
    int f = f0 + (threadIdx.x >> 5), o = threadIdx.x & 31;
    float v = (f < 144) ? S[0][o][f] : S[1][o][f - 144];
    dstbuf[((l * 288 + f) * 32 + i) * 32 + o] = v;
  }
}

// ---------------- forward NUDFT via MFMA (depth-2 prefetch; Ey per-lane from L1) ----------------
__global__ __launch_bounds__(384) void k_fwd_m(const float* __restrict__ hin,
    const float2* __restrict__ ExI, const float2* __restrict__ EyI,
    float* __restrict__ xfr, float* __restrict__ xfi) {
  const int b = blockIdx.y, s = blockIdx.z;
  const int t = threadIdx.x, w = t >> 6, l = t & 63;
  const int mtile = blockIdx.x * 6 + w;          // 0..17
  const int lr = l & 15, lg = l >> 4;
  const int f_row = mtile * 16 + lr;
  const int mp = 23 * (f_row / 12) + (f_row % 12);
  const int irow = mp % 24, jrow = mp / 24;

  __shared__ float2 exs[MX][34];
  __shared__ u16 bh[2][64][8];
  __shared__ u16 bl[2][64][8];

  f4v aR0 = {0.f,0.f,0.f,0.f}, aI0 = {0.f,0.f,0.f,0.f};
  f4v aR1 = {0.f,0.f,0.f,0.f}, aI1 = {0.f,0.f,0.f,0.f};
  const int nbase = s << 8;   // 256-wide K chunk

  const float2* eyrow = EyI + ((size_t)(b * MYK + jrow)) * NPT + lg * 8;

  const int rS = t >> 5, nS = t & 31;
  const int cA = t >> 4, nrA = (t & 15) * 2;
  const int cB = (t + 384) >> 4, nrB = ((t + 384) & 15) * 2;
  const int ctA = cA >> 4, lnA = ((nrA >> 3) << 4) | (cA & 15), eeA = nrA & 7;
  const int ctB = cB >> 4, lnB = ((nrB >> 3) << 4) | (cB & 15), eeB = nrB & 7;

  float2 apx0, apx1, ah2, ah3;
  float2 bpx0, bpx1, bh2, bh3;

#define PFL(kt, px0_, px1_, h2_, h3_) { \
    const int n0_ = nbase + ((kt) << 5); \
    px0_ = ExI[(b * MX + rS) * NPT + n0_ + nS]; \
    px1_ = ExI[(b * MX + rS + 12) * NPT + n0_ + nS]; \
    h2_ = *(const float2*)&hin[((b * CH + cA) << 12) + n0_ + nrA]; \
    if (t < 128) h3_ = *(const float2*)&hin[((b * CH + cB) << 12) + n0_ + nrB]; }

#define STG(px0_, px1_, h2_, h3_) { \
    exs[rS][nS] = px0_; exs[rS + 12][nS] = px1_; \
    u32 hw_, lw_; split2(h2_.x, h2_.y, hw_, lw_); \
    *(u32*)&bh[ctA][lnA][eeA] = hw_; *(u32*)&bl[ctA][lnA][eeA] = lw_; \
    if (t < 128) { u32 hw2_, lw2_; split2(h3_.x, h3_.y, hw2_, lw2_); \
      *(u32*)&bh[ctB][lnB][eeB] = hw2_; *(u32*)&bl[ctB][lnB][eeB] = lw2_; } }

  auto COMPUTE = [&](int n0_) {
    u32x4 rh, rl, ih, il;
    #pragma unroll
    for (int e2 = 0; e2 < 4; ++e2) {
      float4 qx = *(const float4*)&exs[irow][lg * 8 + 2 * e2];
      float4 qy = *(const float4*)&eyrow[n0_ + 2 * e2];
      float vr0 = qx.x * qy.x - qx.y * qy.y;
      float vi0 = qx.x * qy.y + qx.y * qy.x;
      float vr1 = qx.z * qy.z - qx.w * qy.w;
      float vi1 = qx.z * qy.w + qx.w * qy.z;
      u32 w0, w1, w2, w3;
      split2(vr0, vr1, w0, w1);
      split2(vi0, vi1, w2, w3);
      rh[e2] = w0; rl[e2] = w1; ih[e2] = w2; il[e2] = w3;
    }
    s8v arh = __builtin_bit_cast(s8v, rh), arl = __builtin_bit_cast(s8v, rl);
    s8v aih = __builtin_bit_cast(s8v, ih), ail = __builtin_bit_cast(s8v, il);
    s8v b0h = *(const s8v*)(&bh[0][l][0]);
    s8v b0l = *(const s8v*)(&bl[0][l][0]);
    s8v b1h = *(const s8v*)(&bh[1][l][0]);
    s8v b1l = *(const s8v*)(&bl[1][l][0]);
    MF(arh, b0h, aR0); MF(arh, b0l, aR0); MF(arl, b0h, aR0);
    MF(aih, b0h, aI0); MF(aih, b0l, aI0); MF(ail, b0h, aI0);
    MF(arh, b1h, aR1); MF(arh, b1l, aR1); MF(arl, b1h, aR1);
    MF(aih, b1h, aI1); MF(aih, b1l, aI1); MF(ail, b1h, aI1);
  };

  PFL(0, apx0, apx1, ah2, ah3);
  PFL(1, bpx0, bpx1, bh2, bh3);
  #pragma unroll
  for (int kt2 = 0; kt2 < 4; ++kt2) {
    __syncthreads();
    STG(apx0, apx1, ah2, ah3);
    if (kt2 < 3) PFL(2 * kt2 + 2, apx0, apx1, ah2, ah3);
    __syncthreads();
    COMPUTE(nbase + ((2 * kt2) << 5));
    __syncthreads();
    STG(bpx0, bpx1, bh2, bh3);
    if (kt2 < 3) PFL(2 * kt2 + 3, bpx0, bpx1, bh2, bh3);
    __syncthreads();
    COMPUTE(nbase + ((2 * kt2 + 1) << 5));
  }
#undef PFL
#undef STG
  #pragma unroll
  for (int r = 0; r < 4; ++r) {
    int fo = mtile * 16 + lg * 4 + r;
    int base = ((s * BB + b) * NF + fo) * CH + lr;
    xfr[base] = aR0[r]; xfr[base + 16] = aR1[r];
    xfi[base] = aI0[r]; xfi[base + 16] = aI1[r];
  }
}

// ---------------- fullB store helper (pre-split bf16, inv B-fragment layout) ----------------
static __device__ __forceinline__ void fbs(u16* __restrict__ fb, int b, int f, int c, int ri, float v) {
  int kt = f >> 5, kr = f & 31;
  int ct = c >> 4, ln = ((kr >> 3) << 4) | (c & 15), e = kr & 7;
  u16 hi, lo; bsplit(v, hi, lo);
  int off = (b * KTI + kt) * 4096 + ri * 2048 + ct * 512 + ln * 8 + e;
  fb[off] = hi;
  fb[off + 1024] = lo;
}

// ---------------- mode mixing -> F ----------------
__global__ __launch_bounds__(256) void k_mix(const float* __restrict__ xfr, const float* __restrict__ xfi,
    const float* __restrict__ wtr, const float* __restrict__ wti,
    u16* __restrict__ fullB, int l) {
  const int f = blockIdx.x, b = blockIdx.y;
  const int t = threadIdx.x;
  __shared__ float xr_[CH], xi_[CH];
  __shared__ float rr[8][33], ri_[8][33];
  if (t < 64) {
    int i = t & 31, isIm = t >> 5;
    const float* src = isIm ? xfi : xfr;
    float v = 0.f;
    #pragma unroll
    for (int s = 0; s < NS; ++s) v += src[((s * BB + b) * NF + f) * CH + i];
    if (isIm) xi_[i] = v; else xr_[i] = v;
  }
  __syncthreads();
  {
    int o = t & 31, ig = t >> 5;
    float pr = 0.f, pi = 0.f;
    const float* wr_base = wtr + (l * NF + f) * CH * CH;
    const float* wi_base = wti + (l * NF + f) * CH * CH;
    #pragma unroll
    for (int q = 0; q < 4; ++q) {
      int i = ig * 4 + q;
      float xr = xr_[i], xi = xi_[i];
      float w1 = wr_base[i * CH + o], w2 = wi_base[i * CH + o];
      pr += xr * w1 - xi * w2;
      pi += xr * w2 + xi * w1;
    }
    rr[ig][o] = pr; ri_[ig][o] = pi;
  }
  __syncthreads();
  if (t < 64) {
    int o2 = t & 31, isIm = t >> 5;
    float v = 0.f;
    #pragma unroll
    for (int g = 0; g < 8; ++g) v += isIm ? ri_[g][o2] : rr[g][o2];
    fbs(fullB, b, f, o2, isIm, v);
  }
}

// ---------------- inverse NUDFT (K=288, split-K across 8 waves, barrier-light) ----------------
// Waves 0-3 (group 0): rows w*16.., kt 0..3 + S1 + conv.  Waves 4-7 (group 1): same rows, kt 4..8.
// F fragments loaded straight from global (identical across waves, L2-resident).
// Group 1 dumps partial accs to LDS; group 0 combines + epilogue.
__global__ __launch_bounds__(512) void k_inv_m(const float* __restrict__ hin,
    const float2* __restrict__ ExI, const float2* __restrict__ EyI,
    const u16* __restrict__ fullB,
    const u16* __restrict__ cwb, const float* __restrict__ cb,
    float* __restrict__ hout, int l, int doGelu) {
  const int b = blockIdx.y;
  const int n0 = blockIdx.x << 6;
  const int t = threadIdx.x, w = t >> 6, l6 = t & 63;
  const int lr = l6 & 15, lg = l6 >> 4;
  const int wk = w >> 2, wr = w & 3;

  __shared__ float2 exT[64][26];     // [n][i]  (13.3 KB)
  __shared__ float red[256][20];     // group-1 partials (20.5 KB)

  const int nloc = wr * 16 + lr;

  // stage exT with all 512 threads
  for (int e = t; e < MX * 64; e += 512) { int i = e >> 6, nn = e & 63; exT[nn][i] = ExI[(b * MX + i) * NPT + n0 + nn]; }

  // per-lane Ey registers for this group's kts
  const int ktbeg = wk ? 4 : 0, ktend = wk ? KTI : 4;
  float2 eyv[5];
  #pragma unroll
  for (int q = 0; q < 5; ++q) {
    int kt = ktbeg + q;
    if (kt < ktend) {
      int mb = (kt << 5) + (lg << 3);
      int j = (mb * 2731) >> 16;      // mb / 24, <= 11
      eyv[q] = EyI[(b * MYK + j) * NPT + n0 + nloc];
    }
  }

  // group 0 only: conv A-fragment (direct gather) + conv B-fragments
  s8v ah_c, al_c, cwh0, cwh1, cwl0, cwl1;
  if (wk == 0) {
    float hv[8];
    #pragma unroll
    for (int e = 0; e < 8; ++e)
      hv[e] = hin[((b * CH + lg * 8 + e) << 12) + n0 + nloc];
    u32x4 hh, hl2;
    #pragma unroll
    for (int e2 = 0; e2 < 4; ++e2) {
      u32 a_, b_;
      split2(hv[2 * e2], hv[2 * e2 + 1], a_, b_);
      hh[e2] = a_; hl2[e2] = b_;
    }
    ah_c = __builtin_bit_cast(s8v, hh);
    al_c = __builtin_bit_cast(s8v, hl2);
    const u16* cwp = cwb + l * 2048;
    cwh0 = *(const s8v*)(cwp + 0    + l6 * 8);
    cwh1 = *(const s8v*)(cwp + 512  + l6 * 8);
    cwl0 = *(const s8v*)(cwp + 1024 + l6 * 8);
    cwl1 = *(const s8v*)(cwp + 1536 + l6 * 8);
  }

  __syncthreads();   // exT ready

  f4v P0 = {0,0,0,0}, P1 = {0,0,0,0}, B0 = {0,0,0,0}, B1 = {0,0,0,0};
  f4v S1a0 = {0,0,0,0}, S1a1 = {0,0,0,0}, S1b0 = {0,0,0,0}, S1b1 = {0,0,0,0};
  if (wk == 0) {
    MF(ah_c, cwh0, P0); MF(ah_c, cwl0, P0); MF(al_c, cwh0, P0);
    MF(ah_c, cwh1, P1); MF(ah_c, cwl1, P1); MF(al_c, cwh1, P1);
    S1a0 = P0; S1a1 = P1;
  }

  const u16* fbb = fullB + (size_t)(b * KTI) * 4096 + l6 * 8;

  #pragma unroll
  for (int q = 0; q < 5; ++q) {
    int kt = ktbeg + q;
    if (kt >= ktend) break;
    const u16* bp = fbb + kt * 4096;
    s8v Frh0 = *(const s8v*)(bp + 0);
    s8v Frh1 = *(const s8v*)(bp + 512);
    s8v Frl0 = *(const s8v*)(bp + 1024);
    s8v Frl1 = *(const s8v*)(bp + 1536);
    s8v Fih0 = *(const s8v*)(bp + 2048);
    s8v Fih1 = *(const s8v*)(bp + 2560);
    s8v Fil0 = *(const s8v*)(bp + 3072);
    s8v Fil1 = *(const s8v*)(bp + 3584);

    const int mbase = (kt << 5) + (lg << 3);
    const int j = (mbase * 2731) >> 16;
    const int i0 = mbase - 24 * j;
    const float2 ey = eyv[q];
    u32x4 rh, rl, ih, il;
    #pragma unroll
    for (int e2 = 0; e2 < 4; ++e2) {
      float4 qq = *(const float4*)&exT[nloc][i0 + 2 * e2];
      float vr0 = qq.x * ey.x - qq.y * ey.y;
      float vi0 = qq.x * ey.y + qq.y * ey.x;
      float vr1 = qq.z * ey.x - qq.w * ey.y;
      float vi1 = qq.z * ey.y + qq.w * ey.x;
      u32 w0, w1, w2, w3;
      split2(vr0, vr1, w0, w1);
      split2(vi0, vi1, w2, w3);
      rh[e2] = w0; rl[e2] = w1; ih[e2] = w2; il[e2] = w3;
    }
    s8v arh = __builtin_bit_cast(s8v, rh), arl = __builtin_bit_cast(s8v, rl);
    s8v aih = __builtin_bit_cast(s8v, ih), ail = __builtin_bit_cast(s8v, il);
    u32x4 nh = rh ^ 0x80008000u, nl2 = rl ^ 0x80008000u;
    s8v narh = __builtin_bit_cast(s8v, nh), narl = __builtin_bit_cast(s8v, nl2);

    MF(arh, Frh0, P0); MF(arh, Frl0, P0); MF(arl, Frh0, P0);
    MF(aih, Fih0, P0); MF(aih, Fil0, P0); MF(ail, Fih0, P0);
    MF(arh, Frh1, P1); MF(arh, Frl1, P1); MF(arl, Frh1, P1);
    MF(aih, Fih1, P1); MF(aih, Fil1, P1); MF(ail, Fih1, P1);
    MF(aih, Frh0, B0); MF(aih, Frl0, B0); MF(ail, Frh0, B0);
    MF(narh, Fih0, B0); MF(narh, Fil0, B0); MF(narl, Fih0, B0);
    MF(aih, Frh1, B1); MF(aih, Frl1, B1); MF(ail, Frh1, B1);
    MF(narh, Fih1, B1); MF(narh, Fil1, B1); MF(narl, Fih1, B1);
    if (kt == 0) {
      s8v z = {0,0,0,0,0,0,0,0};
      bool live = (lg < 3);
      s8v zrh = live ? arh : z, zrl = live ? arl : z;
      s8v zih = live ? aih : z, zil = live ? ail : z;
      s8v znrh = live ? narh : z, znrl = live ? narl : z;
      MF(zrh, Frh0, S1a0); MF(zrh, Frl0, S1a0); MF(zrl, Frh0, S1a0);
      MF(zih, Fih0, S1a0); MF(zih, Fil0, S1a0); MF(zil, Fih0, S1a0);
      MF(zrh, Frh1, S1a1); MF(zrh, Frl1, S1a1); MF(zrl, Frh1, S1a1);
      MF(zih, Fih1, S1a1); MF(zih, Fil1, S1a1); MF(zil, Fih1, S1a1);
      MF(zih, Frh0, S1b0); MF(zih, Frl0, S1b0); MF(zil, Frh0, S1b0);
      MF(znrh, Fih0, S1b0); MF(znrh, Fil0, S1b0); MF(znrl, Fih0, S1b0);
      MF(zih, Frh1, S1b1); MF(zih, Frl1, S1b1); MF(zil, Frh1, S1b1);
      MF(znrh, Fih1, S1b1); MF(znrh, Fil1, S1b1); MF(znrl, Fih1, S1b1);
    }
  }

  // group 1 -> LDS partials; group 0 combines + epilogue
  if (wk == 1) {
    int row = wr * 64 + l6;
    *(f4v*)&red[row][0]  = P0;
    *(f4v*)&red[row][4]  = P1;
    *(f4v*)&red[row][8]  = B0;
    *(f4v*)&red[row][12] = B1;
  }
  __syncthreads();
  if (wk == 0) {
    int row = wr * 64 + l6;
    P0 += *(const f4v*)&red[row][0];
    P1 += *(const f4v*)&red[row][4];
    B0 += *(const f4v*)&red[row][8];
    B1 += *(const f4v*)&red[row][12];

    float cb0 = cb[l * CH + lr];
    float cb1 = cb[l * CH + 16 + lr];
    #pragma unroll
    for (int r = 0; r < 4; ++r) {
      int nn = wr * 16 + lg * 4 + r;
      float2 e1 = exT[nn][1];                 // SCALE * exp(-i*xs_nn)
      float cs = e1.x * INV_S, sn = -e1.y * INV_S;
      float a20 = P0[r] - S1a0[r], a21 = P1[r] - S1a1[r];
      float b20 = B0[r] - S1b0[r], b21 = B1[r] - S1b1[r];
      float U0r = cs * a20 + sn * b20;
      float U1r = cs * a21 + sn * b21;
      float u1s = __shfl_xor(U1r, 15, 64);
      float u0s = __shfl_xor(U0r, 15, 64);
      float v0 = P0[r] + u1s + cb0;
      float v1 = P1[r] + u0s + cb1;
      if (doGelu) { v0 = gelu_f(v0); v1 = gelu_f(v1); }
      hout[((b * CH + lr) << 12) + n0 + nn] = v0;
      hout[((b * CH + 16 + lr) << 12) + n0 + nn] = v1;
    }
  }
}

// ---------------- final: fc1 + gelu + fc2 ----------------
__global__ __launch_bounds__(256) void k_final(const float* __restrict__ hin,
    const float* __restrict__ fc1w, const float* __restrict__ fc1b,
    const float* __restrict__ fc2w, const float* __restrict__ fc2b, float* __restrict__ out) {
  __shared__ float w1s[CH * 128];
  __shared__ float b1s[128], w2s[128];
  int t = threadIdx.x;
  for (int e = t; e < CH * 128; e += 256) w1s[e] = fc1w[e];
  if (t < 128) { b1s[t] = fc1b[t]; w2s[t] = fc2w[t]; }
  __syncthreads();
  int p = blockIdx.x * 256 + t;
  int b = p >> 12, n = p & (NPT - 1);
  float h[CH];
  #pragma unroll
  for (int c2 = 0; c2 < CH; ++c2) h[c2] = hin[((b * CH + c2) << 12) + n];
  float o = fc2b[0];
  for (int k0 = 0; k0 < 128; k0 += 4) {
    float4 a = *(const float4*)&b1s[k0];
    #pragma unroll
    for (int c2 = 0; c2 < CH; ++c2) {
      float4 wv = *(const float4*)&w1s[c2 * 128 + k0];
      a.x += h[c2] * wv.x; a.y += h[c2] * wv.y;
      a.z += h[c2] * wv.z; a.w += h[c2] * wv.w;
    }
    float4 g = *(const float4*)&w2s[k0];
    o += gelu_f(a.x) * g.x + gelu_f(a.y) * g.y + gelu_f(a.z) * g.z + gelu_f(a.w) * g.w;
  }
  out[p] = o;
}

extern "C" void kernel_launch(void* const* d_in, const int* in_sizes, int n_in,
                              void* d_out, int out_size, void* d_ws, size_t ws_size,
                              hipStream_t stream) {
  const float* pos   = (const float*)d_in[0];
  const float* fc0_w = (const float*)d_in[1];
  const float* fc0_b = (const float*)d_in[2];
  const float* sw1r  = (const float*)d_in[3];
  const float* sw1i  = (const float*)d_in[4];
  const float* sw2r  = (const float*)d_in[5];
  const float* sw2i  = (const float*)d_in[6];
  const float* cw    = (const float*)d_in[7];
  const float* cb    = (const float*)d_in[8];
  const float* fc1_w = (const float*)d_in[9];
  const float* fc1_b = (const float*)d_in[10];
  const float* fc2_w = (const float*)d_in[11];
  const float* fc2_b = (const float*)d_in[12];
  float* out = (float*)d_out;
  float* ws = (float*)d_ws;

  size_t off = 0;
  float* partials = ws;                 off += 256;
  float* scal = ws + off;               off += 16;
  float2* ExI = (float2*)(ws + off);    off += (size_t)BB * MX * NPT * 2;
  float2* EyI = (float2*)(ws + off);    off += (size_t)BB * MYK * NPT * 2;
  float* hA  = ws + off;                off += (size_t)BB * CH * NPT;
  float* hB  = ws + off;                off += (size_t)BB * CH * NPT;
  float* xfr = ws + off;                off += (size_t)NS * BB * NF * CH;
  float* xfi = ws + off;                off += (size_t)NS * BB * NF * CH;
  u16*  fullB = (u16*)(ws + off);       off += (size_t)BB * KTI * 4096 / 2;
  float* wtr = ws + off;                off += (size_t)4 * NF * CH * CH;
  float* wti = ws + off;                off += (size_t)4 * NF * CH * CH;
  u16*  cwb = (u16*)(ws + off);         off += 4096;
  // total ~17.2M floats (~69 MB)

  k_minmax1<<<64, 256, 0, stream>>>(pos, partials);
  k_minmax2<<<1, 64, 0, stream>>>(partials, scal);
  k_setup<<<(BB * NPT) / 256, 256, 0, stream>>>(pos, fc0_w, fc0_b, scal, ExI, EyI, hA);
  k_wtcw<<<260, 256, 0, stream>>>(sw1r, sw1i, sw2r, sw2i, wtr, wti, cw, cwb);

  for (int l = 0; l < 4; ++l) {
    const float* hin = (l & 1) ? hB : hA;
    float* hout = (l & 1) ? hA : hB;
    k_fwd_m<<<dim3(3, BB, NS), 384, 0, stream>>>(hin, ExI, EyI, xfr, xfi);
    k_mix<<<dim3(NF, BB), 256, 0, stream>>>(xfr, xfi, wtr, wti, fullB, l);
    k_inv_m<<<dim3(64, BB), 512, 0, stream>>>(hin, ExI, EyI, fullB, cwb, cb,
                                              hout, l, (l < 3) ? 1 : 0);
  }
  k_final<<<(BB * NPT) / 256, 256, 0, stream>>>(hA, fc1_w, fc1_b, fc2_w, fc2_b, out);
}

// Round 12
// 255.581 us; speedup vs baseline: 1.1375x; 1.1083x over previous
//
#include <hip/hip_runtime.h>
#include <hip/hip_bf16.h>
#include <math.h>

#define BB 16
#define NPT 4096
#define CH 32
#define MX 24      // kx count
#define MYK 23     // ky count
#define NF 288
#define NS 16      // fwd K-split count
#define KTI 9      // inv K-tiles (288/32)
#define SCALE_V 0.022097086912079608f  // sqrt(2)/64
#define INV_S 45.25483399593904f       // 1/SCALE_V

typedef __attribute__((ext_vector_type(8))) short s8v;
typedef __attribute__((ext_vector_type(4))) float f4v;
typedef __attribute__((ext_vector_type(4))) unsigned u32x4;
typedef unsigned short u16;
typedef unsigned int u32;

#define MF(A, B, C) C = __builtin_amdgcn_mfma_f32_16x16x32_bf16(A, B, C, 0, 0, 0)

static __device__ __forceinline__ float gelu_f(float x) {
  return 0.5f * x * (1.0f + erff(x * 0.70710678118654752f));
}

// RNE split (setup-time kernels only)
static __device__ __forceinline__ void bsplit(float v, u16 &hi, u16 &lo) {
  __hip_bfloat16 h = __float2bfloat16(v);
  hi = __builtin_bit_cast(u16, h);
  float r = v - __bfloat162float(h);
  lo = __builtin_bit_cast(u16, __float2bfloat16(r));
}

// truncation split of a PAIR -> packed hi-word and lo-word (6 VALU)
static __device__ __forceinline__ void split2(float v0, float v1, u32 &hw, u32 &lw) {
  u32 b0 = __builtin_bit_cast(u32, v0) & 0xFFFF0000u;
  u32 b1 = __builtin_bit_cast(u32, v1) & 0xFFFF0000u;
  float r0 = v0 - __builtin_bit_cast(float, b0);
  float r1 = v1 - __builtin_bit_cast(float, b1);
  hw = __builtin_amdgcn_perm(b1, b0, 0x07060302u);
  lw = __builtin_amdgcn_perm(__builtin_bit_cast(u32, r1), __builtin_bit_cast(u32, r0), 0x07060302u);
}

// ---------------- min/max reduction ----------------
__global__ void k_minmax1(const float* __restrict__ pos, float* __restrict__ partials) {
  int t = threadIdx.x;
  float mnx = 1e30f, mxx = -1e30f, mny = 1e30f, mxy = -1e30f;
  for (int idx = blockIdx.x * 256 + t; idx < BB * NPT; idx += 64 * 256) {
    float2 p = ((const float2*)pos)[idx];
    mnx = fminf(mnx, p.x); mxx = fmaxf(mxx, p.x);
    mny = fminf(mny, p.y); mxy = fmaxf(mxy, p.y);
  }
  for (int o = 32; o > 0; o >>= 1) {
    mnx = fminf(mnx, __shfl_down(mnx, o));
    mxx = fmaxf(mxx, __shfl_down(mxx, o));
    mny = fminf(mny, __shfl_down(mny, o));
    mxy = fmaxf(mxy, __shfl_down(mxy, o));
  }
  __shared__ float sm[4][4];
  if ((t & 63) == 0) { int wv = t >> 6; sm[wv][0] = mnx; sm[wv][1] = mxx; sm[wv][2] = mny; sm[wv][3] = mxy; }
  __syncthreads();
  if (t == 0) {
    for (int w = 1; w < 4; ++w) {
      mnx = fminf(mnx, sm[w][0]); mxx = fmaxf(mxx, sm[w][1]);
      mny = fminf(mny, sm[w][2]); mxy = fmaxf(mxy, sm[w][3]);
    }
    partials[blockIdx.x * 4 + 0] = mnx; partials[blockIdx.x * 4 + 1] = mxx;
    partials[blockIdx.x * 4 + 2] = mny; partials[blockIdx.x * 4 + 3] = mxy;
  }
}

__global__ void k_minmax2(const float* __restrict__ partials, float* __restrict__ scal) {
  int t = threadIdx.x;  // 64
  float mnx = partials[t * 4 + 0], mxx = partials[t * 4 + 1];
  float mny = partials[t * 4 + 2], mxy = partials[t * 4 + 3];
  for (int o = 32; o > 0; o >>= 1) {
    mnx = fminf(mnx, __shfl_down(mnx, o));
    mxx = fmaxf(mxx, __shfl_down(mxx, o));
    mny = fminf(mny, __shfl_down(mny, o));
    mxy = fmaxf(mxy, __shfl_down(mxy, o));
  }
  if (t == 0) {
    scal[0] = mnx; scal[1] = mny;
    scal[2] = 6.28f / (mxx - mnx);
    scal[3] = 6.28f / (mxy - mny);
  }
}

// ---------------- setup: fc0 + interleaved phasor tables ----------------
__global__ __launch_bounds__(256) void k_setup(const float* __restrict__ pos,
    const float* __restrict__ fc0w, const float* __restrict__ fc0b,
    const float* __restrict__ scal,
    float2* __restrict__ ExI, float2* __restrict__ EyI, float* __restrict__ hA) {
  int p = blockIdx.x * 256 + threadIdx.x;  // 65536
  int b = p >> 12, n = p & (NPT - 1);
  float px = pos[2 * p], py = pos[2 * p + 1];
  float xp = px - scal[0], yp = py - scal[1];
  float xs = xp * scal[2], ys = yp * scal[3];
  #pragma unroll
  for (int c = 0; c < CH; ++c)
    hA[((b * CH + c) << 12) + n] = fmaf(xp, fc0w[c], fmaf(yp, fc0w[32 + c], fc0b[c]));
  float cx, sx_; sincosf(xs, &sx_, &cx);
  ExI[(b * MX + 0) * NPT + n] = make_float2(SCALE_V, 0.f);
  float pr = SCALE_V, pi = 0.f;
  for (int k = 1; k <= 12; ++k) {
    float nr = pr * cx + pi * sx_;
    float ni = pi * cx - pr * sx_;
    pr = nr; pi = ni;
    if (k < 12) {
      ExI[(b * MX + k) * NPT + n] = make_float2(pr, pi);
      ExI[(b * MX + 24 - k) * NPT + n] = make_float2(pr, -pi);
    } else {
      ExI[(b * MX + 12) * NPT + n] = make_float2(pr, -pi);  // kx = -12
    }
  }
  float cy, sy_; sincosf(ys, &sy_, &cy);
  EyI[(b * MYK + 0) * NPT + n] = make_float2(1.f, 0.f);
  float qr = 1.f, qi = 0.f;
  for (int k = 1; k <= 11; ++k) {
    float nr = qr * cy + qi * sy_;
    float ni = qi * cy - qr * sy_;
    qr = nr; qi = ni;
    EyI[(b * MYK + k) * NPT + n] = make_float2(qr, qi);
    EyI[(b * MYK + 23 - k) * NPT + n] = make_float2(qr, -qi);
  }
}

// ---------------- weight transpose + conv-weight + fc1 fragments (merged) ----------------
__global__ __launch_bounds__(256) void k_wtcw(const float* __restrict__ sw1r, const float* __restrict__ sw1i,
    const float* __restrict__ sw2r, const float* __restrict__ sw2i,
    float* __restrict__ wtr, float* __restrict__ wti,
    const float* __restrict__ cw, u16* __restrict__ cwb,
    const float* __restrict__ fc1w, u16* __restrict__ f1b) {
  if (blockIdx.x == 260) {
    // fc1 weights -> pre-split bf16 B-fragments (8 col tiles)
    int t = threadIdx.x;
    for (int idx = t; idx < 4096; idx += 256) {
      int tt = idx >> 9, rem = idx & 511, lane = rem >> 3, e = rem & 7;
      int col = tt * 16 + (lane & 15);
      int c2 = (lane >> 4) * 8 + e;
      float v = fc1w[c2 * 128 + col];
      u16 hi, lo; bsplit(v, hi, lo);
      f1b[tt * 512 + lane * 8 + e] = hi;
      f1b[(8 + tt) * 512 + lane * 8 + e] = lo;
    }
    return;
  }
  if (blockIdx.x >= 256) {
    int l = blockIdx.x - 256, t = threadIdx.x;
    for (int idx = t; idx < 1024; idx += 256) {
      int ct = idx >> 9, rem = idx & 511, lane = rem >> 3, e = rem & 7;
      int o = ct * 16 + (lane & 15);
      int c2 = (lane >> 4) * 8 + e;
      float v = cw[l * 1024 + o * 32 + c2];
      u16 hi, lo; bsplit(v, hi, lo);
      cwb[((l * 2 + 0) * 2 + ct) * 512 + lane * 8 + e] = hi;
      cwb[((l * 2 + 1) * 2 + ct) * 512 + lane * 8 + e] = lo;
    }
    return;
  }
  int l = blockIdx.x >> 6, i = (blockIdx.x >> 1) & 31, a = blockIdx.x & 1;
  __shared__ float S[2][32][145];
  const float* src1 = (a ? sw1i : sw1r) + ((l * 32 + i) * 32) * 144;
  const float* src2 = (a ? sw2i : sw2r) + ((l * 32 + i) * 32) * 144;
  for (int e = threadIdx.x; e < 32 * 144; e += 256) {
    S[0][e / 144][e % 144] = src1[e];
    S[1][e / 144][e % 144] = src2[e];
  }
  __syncthreads();
  float* dstbuf = a ? wti : wtr;
  for (int f0 = 0; f0 < 288; f0 += 8) {
    int f = f0 + (threadIdx.x >> 5), o = threadIdx.x & 31;
    float v = (f < 144) ? S[0][o][f] : S[1][o][f - 144];
    dstbuf[((l * 288 + f) * 32 + i) * 32 + o] = v;
  }
}

// ---------------- forward NUDFT via MFMA (depth-2 prefetch; Ey per-lane from L1) ----------------
__global__ __launch_bounds__(384) void k_fwd_m(const float* __restrict__ hin,
    const float2* __restrict__ ExI, const float2* __restrict__ EyI,
    float* __restrict__ xfr, float* __restrict__ xfi) {
  const int b = blockIdx.y, s = blockIdx.z;
  const int t = threadIdx.x, w = t >> 6, l = t & 63;
  const int mtile = blockIdx.x * 6 + w;          // 0..17
  const int lr = l & 15, lg = l >> 4;
  const int f_row = mtile * 16 + lr;
  const int mp = 23 * (f_row / 12) + (f_row % 12);
  const int irow = mp % 24, jrow = mp / 24;

  __shared__ float2 exs[MX][34];
  __shared__ u16 bh[2][64][8];
  __shared__ u16 bl[2][64][8];

  f4v aR0 = {0.f,0.f,0.f,0.f}, aI0 = {0.f,0.f,0.f,0.f};
  f4v aR1 = {0.f,0.f,0.f,0.f}, aI1 = {0.f,0.f,0.f,0.f};
  const int nbase = s << 8;   // 256-wide K chunk

  const float2* eyrow = EyI + ((size_t)(b * MYK + jrow)) * NPT + lg * 8;

  const int rS = t >> 5, nS = t & 31;
  const int cA = t >> 4, nrA = (t & 15) * 2;
  const int cB = (t + 384) >> 4, nrB = ((t + 384) & 15) * 2;
  const int ctA = cA >> 4, lnA = ((nrA >> 3) << 4) | (cA & 15), eeA = nrA & 7;
  const int ctB = cB >> 4, lnB = ((nrB >> 3) << 4) | (cB & 15), eeB = nrB & 7;

  float2 apx0, apx1, ah2, ah3;
  float2 bpx0, bpx1, bh2, bh3;

#define PFL(kt, px0_, px1_, h2_, h3_) { \
    const int n0_ = nbase + ((kt) << 5); \
    px0_ = ExI[(b * MX + rS) * NPT + n0_ + nS]; \
    px1_ = ExI[(b * MX + rS + 12) * NPT + n0_ + nS]; \
    h2_ = *(const float2*)&hin[((b * CH + cA) << 12) + n0_ + nrA]; \
    if (t < 128) h3_ = *(const float2*)&hin[((b * CH + cB) << 12) + n0_ + nrB]; }

#define STG(px0_, px1_, h2_, h3_) { \
    exs[rS][nS] = px0_; exs[rS + 12][nS] = px1_; \
    u32 hw_, lw_; split2(h2_.x, h2_.y, hw_, lw_); \
    *(u32*)&bh[ctA][lnA][eeA] = hw_; *(u32*)&bl[ctA][lnA][eeA] = lw_; \
    if (t < 128) { u32 hw2_, lw2_; split2(h3_.x, h3_.y, hw2_, lw2_); \
      *(u32*)&bh[ctB][lnB][eeB] = hw2_; *(u32*)&bl[ctB][lnB][eeB] = lw2_; } }

  auto COMPUTE = [&](int n0_) {
    u32x4 rh, rl, ih, il;
    #pragma unroll
    for (int e2 = 0; e2 < 4; ++e2) {
      float4 qx = *(const float4*)&exs[irow][lg * 8 + 2 * e2];
      float4 qy = *(const float4*)&eyrow[n0_ + 2 * e2];
      float vr0 = qx.x * qy.x - qx.y * qy.y;
      float vi0 = qx.x * qy.y + qx.y * qy.x;
      float vr1 = qx.z * qy.z - qx.w * qy.w;
      float vi1 = qx.z * qy.w + qx.w * qy.z;
      u32 w0, w1, w2, w3;
      split2(vr0, vr1, w0, w1);
      split2(vi0, vi1, w2, w3);
      rh[e2] = w0; rl[e2] = w1; ih[e2] = w2; il[e2] = w3;
    }
    s8v arh = __builtin_bit_cast(s8v, rh), arl = __builtin_bit_cast(s8v, rl);
    s8v aih = __builtin_bit_cast(s8v, ih), ail = __builtin_bit_cast(s8v, il);
    s8v b0h = *(const s8v*)(&bh[0][l][0]);
    s8v b0l = *(const s8v*)(&bl[0][l][0]);
    s8v b1h = *(const s8v*)(&bh[1][l][0]);
    s8v b1l = *(const s8v*)(&bl[1][l][0]);
    MF(arh, b0h, aR0); MF(arh, b0l, aR0); MF(arl, b0h, aR0);
    MF(aih, b0h, aI0); MF(aih, b0l, aI0); MF(ail, b0h, aI0);
    MF(arh, b1h, aR1); MF(arh, b1l, aR1); MF(arl, b1h, aR1);
    MF(aih, b1h, aI1); MF(aih, b1l, aI1); MF(ail, b1h, aI1);
  };

  PFL(0, apx0, apx1, ah2, ah3);
  PFL(1, bpx0, bpx1, bh2, bh3);
  #pragma unroll
  for (int kt2 = 0; kt2 < 4; ++kt2) {
    __syncthreads();
    STG(apx0, apx1, ah2, ah3);
    if (kt2 < 3) PFL(2 * kt2 + 2, apx0, apx1, ah2, ah3);
    __syncthreads();
    COMPUTE(nbase + ((2 * kt2) << 5));
    __syncthreads();
    STG(bpx0, bpx1, bh2, bh3);
    if (kt2 < 3) PFL(2 * kt2 + 3, bpx0, bpx1, bh2, bh3);
    __syncthreads();
    COMPUTE(nbase + ((2 * kt2 + 1) << 5));
  }
#undef PFL
#undef STG
  #pragma unroll
  for (int r = 0; r < 4; ++r) {
    int fo = mtile * 16 + lg * 4 + r;
    int base = ((s * BB + b) * NF + fo) * CH + lr;
    xfr[base] = aR0[r]; xfr[base + 16] = aR1[r];
    xfi[base] = aI0[r]; xfi[base + 16] = aI1[r];
  }
}

// ---------------- fullB store helper (pre-split bf16, inv B-fragment layout) ----------------
static __device__ __forceinline__ void fbs(u16* __restrict__ fb, int b, int f, int c, int ri, float v) {
  int kt = f >> 5, kr = f & 31;
  int ct = c >> 4, ln = ((kr >> 3) << 4) | (c & 15), e = kr & 7;
  u16 hi, lo; bsplit(v, hi, lo);
  int off = (b * KTI + kt) * 4096 + ri * 2048 + ct * 512 + ln * 8 + e;
  fb[off] = hi;
  fb[off + 1024] = lo;
}

// ---------------- mode mixing -> F (4 modes per block) ----------------
__global__ __launch_bounds__(256) void k_mix(const float* __restrict__ xfr, const float* __restrict__ xfi,
    const float* __restrict__ wtr, const float* __restrict__ wti,
    u16* __restrict__ fullB, int l) {
  const int b = blockIdx.y;
  const int t = threadIdx.x;
  __shared__ float xr_[CH], xi_[CH];
  __shared__ float rr[8][33], ri_[8][33];
  for (int fq = 0; fq < 4; ++fq) {
    const int f = blockIdx.x * 4 + fq;
    if (t < 64) {
      int i = t & 31, isIm = t >> 5;
      const float* src = isIm ? xfi : xfr;
      float v = 0.f;
      #pragma unroll
      for (int s = 0; s < NS; ++s) v += src[((s * BB + b) * NF + f) * CH + i];
      if (isIm) xi_[i] = v; else xr_[i] = v;
    }
    __syncthreads();
    {
      int o = t & 31, ig = t >> 5;
      float pr = 0.f, pi = 0.f;
      const float* wr_base = wtr + (l * NF + f) * CH * CH;
      const float* wi_base = wti + (l * NF + f) * CH * CH;
      #pragma unroll
      for (int q = 0; q < 4; ++q) {
        int i = ig * 4 + q;
        float xr = xr_[i], xi = xi_[i];
        float w1 = wr_base[i * CH + o], w2 = wi_base[i * CH + o];
        pr += xr * w1 - xi * w2;
        pi += xr * w2 + xi * w1;
      }
      rr[ig][o] = pr; ri_[ig][o] = pi;
    }
    __syncthreads();
    if (t < 64) {
      int o2 = t & 31, isIm = t >> 5;
      float v = 0.f;
      #pragma unroll
      for (int g = 0; g < 8; ++g) v += isIm ? ri_[g][o2] : rr[g][o2];
      fbs(fullB, b, f, o2, isIm, v);
    }
    __syncthreads();
  }
}

// ---------------- inverse NUDFT (K=288, split-K across 8 waves — r11 best) ----------------
__global__ __launch_bounds__(512) void k_inv_m(const float* __restrict__ hin,
    const float2* __restrict__ ExI, const float2* __restrict__ EyI,
    const u16* __restrict__ fullB,
    const u16* __restrict__ cwb, const float* __restrict__ cb,
    float* __restrict__ hout, int l, int doGelu) {
  const int b = blockIdx.y;
  const int n0 = blockIdx.x << 6;
  const int t = threadIdx.x, w = t >> 6, l6 = t & 63;
  const int lr = l6 & 15, lg = l6 >> 4;
  const int wk = w >> 2, wr = w & 3;

  __shared__ float2 exT[64][26];     // [n][i]
  __shared__ float red[256][20];     // group-1 partials

  const int nloc = wr * 16 + lr;

  for (int e = t; e < MX * 64; e += 512) { int i = e >> 6, nn = e & 63; exT[nn][i] = ExI[(b * MX + i) * NPT + n0 + nn]; }

  const int ktbeg = wk ? 4 : 0, ktend = wk ? KTI : 4;
  float2 eyv[5];
  #pragma unroll
  for (int q = 0; q < 5; ++q) {
    int kt = ktbeg + q;
    if (kt < ktend) {
      int mb = (kt << 5) + (lg << 3);
      int j = (mb * 2731) >> 16;
      eyv[q] = EyI[(b * MYK + j) * NPT + n0 + nloc];
    }
  }

  s8v ah_c, al_c, cwh0, cwh1, cwl0, cwl1;
  if (wk == 0) {
    float hv[8];
    #pragma unroll
    for (int e = 0; e < 8; ++e)
      hv[e] = hin[((b * CH + lg * 8 + e) << 12) + n0 + nloc];
    u32x4 hh, hl2;
    #pragma unroll
    for (int e2 = 0; e2 < 4; ++e2) {
      u32 a_, b_;
      split2(hv[2 * e2], hv[2 * e2 + 1], a_, b_);
      hh[e2] = a_; hl2[e2] = b_;
    }
    ah_c = __builtin_bit_cast(s8v, hh);
    al_c = __builtin_bit_cast(s8v, hl2);
    const u16* cwp = cwb + l * 2048;
    cwh0 = *(const s8v*)(cwp + 0    + l6 * 8);
    cwh1 = *(const s8v*)(cwp + 512  + l6 * 8);
    cwl0 = *(const s8v*)(cwp + 1024 + l6 * 8);
    cwl1 = *(const s8v*)(cwp + 1536 + l6 * 8);
  }

  __syncthreads();

  f4v P0 = {0,0,0,0}, P1 = {0,0,0,0}, B0 = {0,0,0,0}, B1 = {0,0,0,0};
  f4v S1a0 = {0,0,0,0}, S1a1 = {0,0,0,0}, S1b0 = {0,0,0,0}, S1b1 = {0,0,0,0};
  if (wk == 0) {
    MF(ah_c, cwh0, P0); MF(ah_c, cwl0, P0); MF(al_c, cwh0, P0);
    MF(ah_c, cwh1, P1); MF(ah_c, cwl1, P1); MF(al_c, cwh1, P1);
    S1a0 = P0; S1a1 = P1;
  }

  const u16* fbb = fullB + (size_t)(b * KTI) * 4096 + l6 * 8;

  #pragma unroll
  for (int q = 0; q < 5; ++q) {
    int kt = ktbeg + q;
    if (kt >= ktend) break;
    const u16* bp = fbb + kt * 4096;
    s8v Frh0 = *(const s8v*)(bp + 0);
    s8v Frh1 = *(const s8v*)(bp + 512);
    s8v Frl0 = *(const s8v*)(bp + 1024);
    s8v Frl1 = *(const s8v*)(bp + 1536);
    s8v Fih0 = *(const s8v*)(bp + 2048);
    s8v Fih1 = *(const s8v*)(bp + 2560);
    s8v Fil0 = *(const s8v*)(bp + 3072);
    s8v Fil1 = *(const s8v*)(bp + 3584);

    const int mbase = (kt << 5) + (lg << 3);
    const int j = (mbase * 2731) >> 16;
    const int i0 = mbase - 24 * j;
    const float2 ey = eyv[q];
    u32x4 rh, rl, ih, il;
    #pragma unroll
    for (int e2 = 0; e2 < 4; ++e2) {
      float4 qq = *(const float4*)&exT[nloc][i0 + 2 * e2];
      float vr0 = qq.x * ey.x - qq.y * ey.y;
      float vi0 = qq.x * ey.y + qq.y * ey.x;
      float vr1 = qq.z * ey.x - qq.w * ey.y;
      float vi1 = qq.z * ey.y + qq.w * ey.x;
      u32 w0, w1, w2, w3;
      split2(vr0, vr1, w0, w1);
      split2(vi0, vi1, w2, w3);
      rh[e2] = w0; rl[e2] = w1; ih[e2] = w2; il[e2] = w3;
    }
    s8v arh = __builtin_bit_cast(s8v, rh), arl = __builtin_bit_cast(s8v, rl);
    s8v aih = __builtin_bit_cast(s8v, ih), ail = __builtin_bit_cast(s8v, il);
    u32x4 nh = rh ^ 0x80008000u, nl2 = rl ^ 0x80008000u;
    s8v narh = __builtin_bit_cast(s8v, nh), narl = __builtin_bit_cast(s8v, nl2);

    MF(arh, Frh0, P0); MF(arh, Frl0, P0); MF(arl, Frh0, P0);
    MF(aih, Fih0, P0); MF(aih, Fil0, P0); MF(ail, Fih0, P0);
    MF(arh, Frh1, P1); MF(arh, Frl1, P1); MF(arl, Frh1, P1);
    MF(aih, Fih1, P1); MF(aih, Fil1, P1); MF(ail, Fih1, P1);
    MF(aih, Frh0, B0); MF(aih, Frl0, B0); MF(ail, Frh0, B0);
    MF(narh, Fih0, B0); MF(narh, Fil0, B0); MF(narl, Fih0, B0);
    MF(aih, Frh1, B1); MF(aih, Frl1, B1); MF(ail, Frh1, B1);
    MF(narh, Fih1, B1); MF(narh, Fil1, B1); MF(narl, Fih1, B1);
    if (kt == 0) {
      s8v z = {0,0,0,0,0,0,0,0};
      bool live = (lg < 3);
      s8v zrh = live ? arh : z, zrl = live ? arl : z;
      s8v zih = live ? aih : z, zil = live ? ail : z;
      s8v znrh = live ? narh : z, znrl = live ? narl : z;
      MF(zrh, Frh0, S1a0); MF(zrh, Frl0, S1a0); MF(zrl, Frh0, S1a0);
      MF(zih, Fih0, S1a0); MF(zih, Fil0, S1a0); MF(zil, Fih0, S1a0);
      MF(zrh, Frh1, S1a1); MF(zrh, Frl1, S1a1); MF(zrl, Frh1, S1a1);
      MF(zih, Fih1, S1a1); MF(zih, Fil1, S1a1); MF(zil, Fih1, S1a1);
      MF(zih, Frh0, S1b0); MF(zih, Frl0, S1b0); MF(zil, Frh0, S1b0);
      MF(znrh, Fih0, S1b0); MF(znrh, Fil0, S1b0); MF(znrl, Fih0, S1b0);
      MF(zih, Frh1, S1b1); MF(zih, Frl1, S1b1); MF(zil, Frh1, S1b1);
      MF(znrh, Fih1, S1b1); MF(znrh, Fil1, S1b1); MF(znrl, Fih1, S1b1);
    }
  }

  if (wk == 1) {
    int row = wr * 64 + l6;
    *(f4v*)&red[row][0]  = P0;
    *(f4v*)&red[row][4]  = P1;
    *(f4v*)&red[row][8]  = B0;
    *(f4v*)&red[row][12] = B1;
  }
  __syncthreads();
  if (wk == 0) {
    int row = wr * 64 + l6;
    P0 += *(const f4v*)&red[row][0];
    P1 += *(const f4v*)&red[row][4];
    B0 += *(const f4v*)&red[row][8];
    B1 += *(const f4v*)&red[row][12];

    float cb0 = cb[l * CH + lr];
    float cb1 = cb[l * CH + 16 + lr];
    #pragma unroll
    for (int r = 0; r < 4; ++r) {
      int nn = wr * 16 + lg * 4 + r;
      float2 e1 = exT[nn][1];                 // SCALE * exp(-i*xs_nn)
      float cs = e1.x * INV_S, sn = -e1.y * INV_S;
      float a20 = P0[r] - S1a0[r], a21 = P1[r] - S1a1[r];
      float b20 = B0[r] - S1b0[r], b21 = B1[r] - S1b1[r];
      float U0r = cs * a20 + sn * b20;
      float U1r = cs * a21 + sn * b21;
      float u1s = __shfl_xor(U1r, 15, 64);
      float u0s = __shfl_xor(U0r, 15, 64);
      float v0 = P0[r] + u1s + cb0;
      float v1 = P1[r] + u0s + cb1;
      if (doGelu) { v0 = gelu_f(v0); v1 = gelu_f(v1); }
      hout[((b * CH + lr) << 12) + n0 + nn] = v0;
      hout[((b * CH + 16 + lr) << 12) + n0 + nn] = v1;
    }
  }
}

// ---------------- final: fc1 (MFMA) + gelu + fc2 ----------------
__global__ __launch_bounds__(256) void k_final_m(const float* __restrict__ hin,
    const u16* __restrict__ f1b, const float* __restrict__ fc1b_,
    const float* __restrict__ fc2w, const float* __restrict__ fc2b,
    float* __restrict__ out) {
  const int b = blockIdx.y;
  const int n0 = blockIdx.x << 6;
  const int t = threadIdx.x, w = t >> 6, l6 = t & 63;
  const int lr = l6 & 15, lg = l6 >> 4;
  const int nloc = w * 16 + lr;

  // A-frag: h[nloc][c = lg*8 + e] (direct gather)
  s8v ah, al;
  {
    float hv[8];
    #pragma unroll
    for (int e = 0; e < 8; ++e)
      hv[e] = hin[((b * CH + lg * 8 + e) << 12) + n0 + nloc];
    u32x4 hh, hl2;
    #pragma unroll
    for (int e2 = 0; e2 < 4; ++e2) {
      u32 a_, b_;
      split2(hv[2 * e2], hv[2 * e2 + 1], a_, b_);
      hh[e2] = a_; hl2[e2] = b_;
    }
    ah = __builtin_bit_cast(s8v, hh);
    al = __builtin_bit_cast(s8v, hl2);
  }

  float acc[4] = {0.f, 0.f, 0.f, 0.f};
  #pragma unroll
  for (int tt = 0; tt < 8; ++tt) {
    s8v Bh = *(const s8v*)(f1b + tt * 512 + l6 * 8);
    s8v Bl = *(const s8v*)(f1b + (8 + tt) * 512 + l6 * 8);
    f4v D = {0.f, 0.f, 0.f, 0.f};
    MF(ah, Bh, D); MF(ah, Bl, D); MF(al, Bh, D);
    float b1v = fc1b_[tt * 16 + lr];
    float w2v = fc2w[tt * 16 + lr];
    #pragma unroll
    for (int r = 0; r < 4; ++r) acc[r] += gelu_f(D[r] + b1v) * w2v;
  }
  float ob = fc2b[0];
  #pragma unroll
  for (int r = 0; r < 4; ++r) {
    float v = acc[r];
    v += __shfl_xor(v, 1, 64);
    v += __shfl_xor(v, 2, 64);
    v += __shfl_xor(v, 4, 64);
    v += __shfl_xor(v, 8, 64);
    if (lr == 0) out[(b << 12) + n0 + w * 16 + lg * 4 + r] = v + ob;
  }
}

extern "C" void kernel_launch(void* const* d_in, const int* in_sizes, int n_in,
                              void* d_out, int out_size, void* d_ws, size_t ws_size,
                              hipStream_t stream) {
  const float* pos   = (const float*)d_in[0];
  const float* fc0_w = (const float*)d_in[1];
  const float* fc0_b = (const float*)d_in[2];
  const float* sw1r  = (const float*)d_in[3];
  const float* sw1i  = (const float*)d_in[4];
  const float* sw2r  = (const float*)d_in[5];
  const float* sw2i  = (const float*)d_in[6];
  const float* cw    = (const float*)d_in[7];
  const float* cb    = (const float*)d_in[8];
  const float* fc1_w = (const float*)d_in[9];
  const float* fc1_b = (const float*)d_in[10];
  const float* fc2_w = (const float*)d_in[11];
  const float* fc2_b = (const float*)d_in[12];
  float* out = (float*)d_out;
  float* ws = (float*)d_ws;

  size_t off = 0;
  float* partials = ws;                 off += 256;
  float* scal = ws + off;               off += 16;
  float2* ExI = (float2*)(ws + off);    off += (size_t)BB * MX * NPT * 2;
  float2* EyI = (float2*)(ws + off);    off += (size_t)BB * MYK * NPT * 2;
  float* hA  = ws + off;                off += (size_t)BB * CH * NPT;
  float* hB  = ws + off;                off += (size_t)BB * CH * NPT;
  float* xfr = ws + off;                off += (size_t)NS * BB * NF * CH;
  float* xfi = ws + off;                off += (size_t)NS * BB * NF * CH;
  u16*  fullB = (u16*)(ws + off);       off += (size_t)BB * KTI * 4096 / 2;
  float* wtr = ws + off;                off += (size_t)4 * NF * CH * CH;
  float* wti = ws + off;                off += (size_t)4 * NF * CH * CH;
  u16*  cwb = (u16*)(ws + off);         off += 4096;
  u16*  f1b = (u16*)(ws + off);         off += 4096;   // 8192 u16
  // total ~17.2M floats (~69 MB)

  k_minmax1<<<64, 256, 0, stream>>>(pos, partials);
  k_minmax2<<<1, 64, 0, stream>>>(partials, scal);
  k_setup<<<(BB * NPT) / 256, 256, 0, stream>>>(pos, fc0_w, fc0_b, scal, ExI, EyI, hA);
  k_wtcw<<<261, 256, 0, stream>>>(sw1r, sw1i, sw2r, sw2i, wtr, wti, cw, cwb, fc1_w, f1b);

  for (int l = 0; l < 4; ++l) {
    const float* hin = (l & 1) ? hB : hA;
    float* hout = (l & 1) ? hA : hB;
    k_fwd_m<<<dim3(3, BB, NS), 384, 0, stream>>>(hin, ExI, EyI, xfr, xfi);
    k_mix<<<dim3(NF / 4, BB), 256, 0, stream>>>(xfr, xfi, wtr, wti, fullB, l);
    k_inv_m<<<dim3(64, BB), 512, 0, stream>>>(hin, ExI, EyI, fullB, cwb, cb,
                                              hout, l, (l < 3) ? 1 : 0);
  }
  k_final_m<<<dim3(64, BB), 256, 0, stream>>>(hA, f1b, fc1_b, fc2_w, fc2_b, out);
}

// Round 13
// 240.971 us; speedup vs baseline: 1.2065x; 1.0606x over previous
//
#include <hip/hip_runtime.h>
#include <hip/hip_bf16.h>
#include <math.h>

#define BB 16
#define NPT 4096
#define CH 32
#define MX 24      // kx count
#define MYK 23     // ky count
#define NF 288
#define NS 16      // fwd K-split count
#define KTI 9      // inv K-tiles (288/32)
#define SCALE_V 0.022097086912079608f  // sqrt(2)/64
#define INV_S 45.25483399593904f       // 1/SCALE_V

typedef __attribute__((ext_vector_type(8))) short s8v;
typedef __attribute__((ext_vector_type(4))) float f4v;
typedef __attribute__((ext_vector_type(4))) unsigned u32x4;
typedef unsigned short u16;
typedef unsigned int u32;

#define MF(A, B, C) C = __builtin_amdgcn_mfma_f32_16x16x32_bf16(A, B, C, 0, 0, 0)

static __device__ __forceinline__ float gelu_f(float x) {
  return 0.5f * x * (1.0f + erff(x * 0.70710678118654752f));
}

// RNE split (setup-time kernels only)
static __device__ __forceinline__ void bsplit(float v, u16 &hi, u16 &lo) {
  __hip_bfloat16 h = __float2bfloat16(v);
  hi = __builtin_bit_cast(u16, h);
  float r = v - __bfloat162float(h);
  lo = __builtin_bit_cast(u16, __float2bfloat16(r));
}

// truncation split of a PAIR -> packed hi-word and lo-word (6 VALU)
static __device__ __forceinline__ void split2(float v0, float v1, u32 &hw, u32 &lw) {
  u32 b0 = __builtin_bit_cast(u32, v0) & 0xFFFF0000u;
  u32 b1 = __builtin_bit_cast(u32, v1) & 0xFFFF0000u;
  float r0 = v0 - __builtin_bit_cast(float, b0);
  float r1 = v1 - __builtin_bit_cast(float, b1);
  hw = __builtin_amdgcn_perm(b1, b0, 0x07060302u);
  lw = __builtin_amdgcn_perm(__builtin_bit_cast(u32, r1), __builtin_bit_cast(u32, r0), 0x07060302u);
}

// ---------------- min/max reduction ----------------
__global__ void k_minmax1(const float* __restrict__ pos, float* __restrict__ partials) {
  int t = threadIdx.x;
  float mnx = 1e30f, mxx = -1e30f, mny = 1e30f, mxy = -1e30f;
  for (int idx = blockIdx.x * 256 + t; idx < BB * NPT; idx += 64 * 256) {
    float2 p = ((const float2*)pos)[idx];
    mnx = fminf(mnx, p.x); mxx = fmaxf(mxx, p.x);
    mny = fminf(mny, p.y); mxy = fmaxf(mxy, p.y);
  }
  for (int o = 32; o > 0; o >>= 1) {
    mnx = fminf(mnx, __shfl_down(mnx, o));
    mxx = fmaxf(mxx, __shfl_down(mxx, o));
    mny = fminf(mny, __shfl_down(mny, o));
    mxy = fmaxf(mxy, __shfl_down(mxy, o));
  }
  __shared__ float sm[4][4];
  if ((t & 63) == 0) { int wv = t >> 6; sm[wv][0] = mnx; sm[wv][1] = mxx; sm[wv][2] = mny; sm[wv][3] = mxy; }
  __syncthreads();
  if (t == 0) {
    for (int w = 1; w < 4; ++w) {
      mnx = fminf(mnx, sm[w][0]); mxx = fmaxf(mxx, sm[w][1]);
      mny = fminf(mny, sm[w][2]); mxy = fmaxf(mxy, sm[w][3]);
    }
    partials[blockIdx.x * 4 + 0] = mnx; partials[blockIdx.x * 4 + 1] = mxx;
    partials[blockIdx.x * 4 + 2] = mny; partials[blockIdx.x * 4 + 3] = mxy;
  }
}

__global__ void k_minmax2(const float* __restrict__ partials, float* __restrict__ scal) {
  int t = threadIdx.x;  // 64
  float mnx = partials[t * 4 + 0], mxx = partials[t * 4 + 1];
  float mny = partials[t * 4 + 2], mxy = partials[t * 4 + 3];
  for (int o = 32; o > 0; o >>= 1) {
    mnx = fminf(mnx, __shfl_down(mnx, o));
    mxx = fmaxf(mxx, __shfl_down(mxx, o));
    mny = fminf(mny, __shfl_down(mny, o));
    mxy = fmaxf(mxy, __shfl_down(mxy, o));
  }
  if (t == 0) {
    scal[0] = mnx; scal[1] = mny;
    scal[2] = 6.28f / (mxx - mnx);
    scal[3] = 6.28f / (mxy - mny);
  }
}

// ---------------- setup: fc0 + interleaved phasor tables ----------------
__global__ __launch_bounds__(256) void k_setup(const float* __restrict__ pos,
    const float* __restrict__ fc0w, const float* __restrict__ fc0b,
    const float* __restrict__ scal,
    float2* __restrict__ ExI, float2* __restrict__ EyI, float* __restrict__ hA) {
  int p = blockIdx.x * 256 + threadIdx.x;  // 65536
  int b = p >> 12, n = p & (NPT - 1);
  float px = pos[2 * p], py = pos[2 * p + 1];
  float xp = px - scal[0], yp = py - scal[1];
  float xs = xp * scal[2], ys = yp * scal[3];
  #pragma unroll
  for (int c = 0; c < CH; ++c)
    hA[((b * CH + c) << 12) + n] = fmaf(xp, fc0w[c], fmaf(yp, fc0w[32 + c], fc0b[c]));
  float cx, sx_; sincosf(xs, &sx_, &cx);
  ExI[(b * MX + 0) * NPT + n] = make_float2(SCALE_V, 0.f);
  float pr = SCALE_V, pi = 0.f;
  for (int k = 1; k <= 12; ++k) {
    float nr = pr * cx + pi * sx_;
    float ni = pi * cx - pr * sx_;
    pr = nr; pi = ni;
    if (k < 12) {
      ExI[(b * MX + k) * NPT + n] = make_float2(pr, pi);
      ExI[(b * MX + 24 - k) * NPT + n] = make_float2(pr, -pi);
    } else {
      ExI[(b * MX + 12) * NPT + n] = make_float2(pr, -pi);  // kx = -12
    }
  }
  float cy, sy_; sincosf(ys, &sy_, &cy);
  EyI[(b * MYK + 0) * NPT + n] = make_float2(1.f, 0.f);
  float qr = 1.f, qi = 0.f;
  for (int k = 1; k <= 11; ++k) {
    float nr = qr * cy + qi * sy_;
    float ni = qi * cy - qr * sy_;
    qr = nr; qi = ni;
    EyI[(b * MYK + k) * NPT + n] = make_float2(qr, qi);
    EyI[(b * MYK + 23 - k) * NPT + n] = make_float2(qr, -qi);
  }
}

// ---------------- weight transpose + conv-weight + fc1 fragments (merged) ----------------
__global__ __launch_bounds__(256) void k_wtcw(const float* __restrict__ sw1r, const float* __restrict__ sw1i,
    const float* __restrict__ sw2r, const float* __restrict__ sw2i,
    float* __restrict__ wtr, float* __restrict__ wti,
    const float* __restrict__ cw, u16* __restrict__ cwb,
    const float* __restrict__ fc1w, u16* __restrict__ f1b) {
  if (blockIdx.x == 260) {
    // fc1 weights -> pre-split bf16 B-fragments (8 col tiles)
    int t = threadIdx.x;
    for (int idx = t; idx < 4096; idx += 256) {
      int tt = idx >> 9, rem = idx & 511, lane = rem >> 3, e = rem & 7;
      int col = tt * 16 + (lane & 15);
      int c2 = (lane >> 4) * 8 + e;
      float v = fc1w[c2 * 128 + col];
      u16 hi, lo; bsplit(v, hi, lo);
      f1b[tt * 512 + lane * 8 + e] = hi;
      f1b[(8 + tt) * 512 + lane * 8 + e] = lo;
    }
    return;
  }
  if (blockIdx.x >= 256) {
    int l = blockIdx.x - 256, t = threadIdx.x;
    for (int idx = t; idx < 1024; idx += 256) {
      int ct = idx >> 9, rem = idx & 511, lane = rem >> 3, e = rem & 7;
      int o = ct * 16 + (lane & 15);
      int c2 = (lane >> 4) * 8 + e;
      float v = cw[l * 1024 + o * 32 + c2];
      u16 hi, lo; bsplit(v, hi, lo);
      cwb[((l * 2 + 0) * 2 + ct) * 512 + lane * 8 + e] = hi;
      cwb[((l * 2 + 1) * 2 + ct) * 512 + lane * 8 + e] = lo;
    }
    return;
  }
  int l = blockIdx.x >> 6, i = (blockIdx.x >> 1) & 31, a = blockIdx.x & 1;
  __shared__ float S[2][32][145];
  const float* src1 = (a ? sw1i : sw1r) + ((l * 32 + i) * 32) * 144;
  const float* src2 = (a ? sw2i : sw2r) + ((l * 32 + i) * 32) * 144;
  for (int e = threadIdx.x; e < 32 * 144; e += 256) {
    S[0][e / 144][e % 144] = src1[e];
    S[1][e / 144][e % 144] = src2[e];
  }
  __syncthreads();
  float* dstbuf = a ? wti : wtr;
  for (int f0 = 0; f0 < 288; f0 += 8) {
    int f = f0 + (threadIdx.x >> 5), o = threadIdx.x & 31;
    float v = (f < 144) ? S[0][o][f] : S[1][o][f - 144];
    dstbuf[((l * 288 + f) * 32 + i) * 32 + o] = v;
  }
}

// ---------------- forward NUDFT via MFMA (depth-2 prefetch; Ey prefetched to regs) ----------------
__global__ __launch_bounds__(384) void k_fwd_m(const float* __restrict__ hin,
    const float2* __restrict__ ExI, const float2* __restrict__ EyI,
    float* __restrict__ xfr, float* __restrict__ xfi) {
  const int b = blockIdx.y, s = blockIdx.z;
  const int t = threadIdx.x, w = t >> 6, l = t & 63;
  const int mtile = blockIdx.x * 6 + w;          // 0..17
  const int lr = l & 15, lg = l >> 4;
  const int f_row = mtile * 16 + lr;
  const int mp = 23 * (f_row / 12) + (f_row % 12);
  const int irow = mp % 24, jrow = mp / 24;

  __shared__ float2 exs[MX][34];
  __shared__ u16 bh[2][64][8];
  __shared__ u16 bl[2][64][8];

  f4v aR0 = {0.f,0.f,0.f,0.f}, aI0 = {0.f,0.f,0.f,0.f};
  f4v aR1 = {0.f,0.f,0.f,0.f}, aI1 = {0.f,0.f,0.f,0.f};
  const int nbase = s << 8;   // 256-wide K chunk

  const float2* eyrow = EyI + ((size_t)(b * MYK + jrow)) * NPT + lg * 8;

  const int rS = t >> 5, nS = t & 31;
  const int cA = t >> 4, nrA = (t & 15) * 2;
  const int cB = (t + 384) >> 4, nrB = ((t + 384) & 15) * 2;
  const int ctA = cA >> 4, lnA = ((nrA >> 3) << 4) | (cA & 15), eeA = nrA & 7;
  const int ctB = cB >> 4, lnB = ((nrB >> 3) << 4) | (cB & 15), eeB = nrB & 7;

  float2 apx0, apx1, ah2, ah3;
  float2 bpx0, bpx1, bh2, bh3;
  float4 qA0, qA1, qA2, qA3;     // Ey prefetch set A
  float4 qB0, qB1, qB2, qB3;     // Ey prefetch set B

#define PFL(kt, px0_, px1_, h2_, h3_) { \
    const int n0_ = nbase + ((kt) << 5); \
    px0_ = ExI[(b * MX + rS) * NPT + n0_ + nS]; \
    px1_ = ExI[(b * MX + rS + 12) * NPT + n0_ + nS]; \
    h2_ = *(const float2*)&hin[((b * CH + cA) << 12) + n0_ + nrA]; \
    if (t < 128) h3_ = *(const float2*)&hin[((b * CH + cB) << 12) + n0_ + nrB]; }

#define PFLQ(kt, q0_, q1_, q2_, q3_) { \
    const int n0_ = nbase + ((kt) << 5); \
    q0_ = *(const float4*)&eyrow[n0_]; \
    q1_ = *(const float4*)&eyrow[n0_ + 2]; \
    q2_ = *(const float4*)&eyrow[n0_ + 4]; \
    q3_ = *(const float4*)&eyrow[n0_ + 6]; }

#define STG(px0_, px1_, h2_, h3_) { \
    exs[rS][nS] = px0_; exs[rS + 12][nS] = px1_; \
    u32 hw_, lw_; split2(h2_.x, h2_.y, hw_, lw_); \
    *(u32*)&bh[ctA][lnA][eeA] = hw_; *(u32*)&bl[ctA][lnA][eeA] = lw_; \
    if (t < 128) { u32 hw2_, lw2_; split2(h3_.x, h3_.y, hw2_, lw2_); \
      *(u32*)&bh[ctB][lnB][eeB] = hw2_; *(u32*)&bl[ctB][lnB][eeB] = lw2_; } }

  auto COMPUTE = [&](float4 q0_, float4 q1_, float4 q2_, float4 q3_) {
    u32x4 rh, rl, ih, il;
    #pragma unroll
    for (int e2 = 0; e2 < 4; ++e2) {
      float4 qx = *(const float4*)&exs[irow][lg * 8 + 2 * e2];
      float4 qy = (e2 == 0) ? q0_ : (e2 == 1) ? q1_ : (e2 == 2) ? q2_ : q3_;
      float vr0 = qx.x * qy.x - qx.y * qy.y;
      float vi0 = qx.x * qy.y + qx.y * qy.x;
      float vr1 = qx.z * qy.z - qx.w * qy.w;
      float vi1 = qx.z * qy.w + qx.w * qy.z;
      u32 w0, w1, w2, w3;
      split2(vr0, vr1, w0, w1);
      split2(vi0, vi1, w2, w3);
      rh[e2] = w0; rl[e2] = w1; ih[e2] = w2; il[e2] = w3;
    }
    s8v arh = __builtin_bit_cast(s8v, rh), arl = __builtin_bit_cast(s8v, rl);
    s8v aih = __builtin_bit_cast(s8v, ih), ail = __builtin_bit_cast(s8v, il);
    s8v b0h = *(const s8v*)(&bh[0][l][0]);
    s8v b0l = *(const s8v*)(&bl[0][l][0]);
    s8v b1h = *(const s8v*)(&bh[1][l][0]);
    s8v b1l = *(const s8v*)(&bl[1][l][0]);
    MF(arh, b0h, aR0); MF(arh, b0l, aR0); MF(arl, b0h, aR0);
    MF(aih, b0h, aI0); MF(aih, b0l, aI0); MF(ail, b0h, aI0);
    MF(arh, b1h, aR1); MF(arh, b1l, aR1); MF(arl, b1h, aR1);
    MF(aih, b1h, aI1); MF(aih, b1l, aI1); MF(ail, b1h, aI1);
  };

  PFL(0, apx0, apx1, ah2, ah3);  PFLQ(0, qA0, qA1, qA2, qA3);
  PFL(1, bpx0, bpx1, bh2, bh3);  PFLQ(1, qB0, qB1, qB2, qB3);
  #pragma unroll
  for (int kt2 = 0; kt2 < 4; ++kt2) {
    __syncthreads();
    STG(apx0, apx1, ah2, ah3);
    if (kt2 < 3) PFL(2 * kt2 + 2, apx0, apx1, ah2, ah3);
    __syncthreads();
    COMPUTE(qA0, qA1, qA2, qA3);
    if (kt2 < 3) PFLQ(2 * kt2 + 2, qA0, qA1, qA2, qA3);
    __syncthreads();
    STG(bpx0, bpx1, bh2, bh3);
    if (kt2 < 3) PFL(2 * kt2 + 3, bpx0, bpx1, bh2, bh3);
    __syncthreads();
    COMPUTE(qB0, qB1, qB2, qB3);
    if (kt2 < 3) PFLQ(2 * kt2 + 3, qB0, qB1, qB2, qB3);
  }
#undef PFL
#undef PFLQ
#undef STG
  #pragma unroll
  for (int r = 0; r < 4; ++r) {
    int fo = mtile * 16 + lg * 4 + r;
    int base = ((s * BB + b) * NF + fo) * CH + lr;
    xfr[base] = aR0[r]; xfr[base + 16] = aR1[r];
    xfi[base] = aI0[r]; xfi[base + 16] = aI1[r];
  }
}

// ---------------- fullB store helper (pre-split bf16, inv B-fragment layout) ----------------
static __device__ __forceinline__ void fbs(u16* __restrict__ fb, int b, int f, int c, int ri, float v) {
  int kt = f >> 5, kr = f & 31;
  int ct = c >> 4, ln = ((kr >> 3) << 4) | (c & 15), e = kr & 7;
  u16 hi, lo; bsplit(v, hi, lo);
  int off = (b * KTI + kt) * 4096 + ri * 2048 + ct * 512 + ln * 8 + e;
  fb[off] = hi;
  fb[off + 1024] = lo;
}

// ---------------- mode mixing -> F (4 modes per block) ----------------
__global__ __launch_bounds__(256) void k_mix(const float* __restrict__ xfr, const float* __restrict__ xfi,
    const float* __restrict__ wtr, const float* __restrict__ wti,
    u16* __restrict__ fullB, int l) {
  const int b = blockIdx.y;
  const int t = threadIdx.x;
  __shared__ float xr_[CH], xi_[CH];
  __shared__ float rr[8][33], ri_[8][33];
  for (int fq = 0; fq < 4; ++fq) {
    const int f = blockIdx.x * 4 + fq;
    if (t < 64) {
      int i = t & 31, isIm = t >> 5;
      const float* src = isIm ? xfi : xfr;
      float v = 0.f;
      #pragma unroll
      for (int s = 0; s < NS; ++s) v += src[((s * BB + b) * NF + f) * CH + i];
      if (isIm) xi_[i] = v; else xr_[i] = v;
    }
    __syncthreads();
    {
      int o = t & 31, ig = t >> 5;
      float pr = 0.f, pi = 0.f;
      const float* wr_base = wtr + (l * NF + f) * CH * CH;
      const float* wi_base = wti + (l * NF + f) * CH * CH;
      #pragma unroll
      for (int q = 0; q < 4; ++q) {
        int i = ig * 4 + q;
        float xr = xr_[i], xi = xi_[i];
        float w1 = wr_base[i * CH + o], w2 = wi_base[i * CH + o];
        pr += xr * w1 - xi * w2;
        pi += xr * w2 + xi * w1;
      }
      rr[ig][o] = pr; ri_[ig][o] = pi;
    }
    __syncthreads();
    if (t < 64) {
      int o2 = t & 31, isIm = t >> 5;
      float v = 0.f;
      #pragma unroll
      for (int g = 0; g < 8; ++g) v += isIm ? ri_[g][o2] : rr[g][o2];
      fbs(fullB, b, f, o2, isIm, v);
    }
    __syncthreads();
  }
}

// ---------------- inverse NUDFT (K=288, split-K across 8 waves — r11 best) ----------------
__global__ __launch_bounds__(512) void k_inv_m(const float* __restrict__ hin,
    const float2* __restrict__ ExI, const float2* __restrict__ EyI,
    const u16* __restrict__ fullB,
    const u16* __restrict__ cwb, const float* __restrict__ cb,
    float* __restrict__ hout, int l, int doGelu) {
  const int b = blockIdx.y;
  const int n0 = blockIdx.x << 6;
  const int t = threadIdx.x, w = t >> 6, l6 = t & 63;
  const int lr = l6 & 15, lg = l6 >> 4;
  const int wk = w >> 2, wr = w & 3;

  __shared__ float2 exT[64][26];     // [n][i]
  __shared__ float red[256][20];     // group-1 partials

  const int nloc = wr * 16 + lr;

  for (int e = t; e < MX * 64; e += 512) { int i = e >> 6, nn = e & 63; exT[nn][i] = ExI[(b * MX + i) * NPT + n0 + nn]; }

  const int ktbeg = wk ? 4 : 0, ktend = wk ? KTI : 4;
  float2 eyv[5];
  #pragma unroll
  for (int q = 0; q < 5; ++q) {
    int kt = ktbeg + q;
    if (kt < ktend) {
      int mb = (kt << 5) + (lg << 3);
      int j = (mb * 2731) >> 16;
      eyv[q] = EyI[(b * MYK + j) * NPT + n0 + nloc];
    }
  }

  s8v ah_c, al_c, cwh0, cwh1, cwl0, cwl1;
  if (wk == 0) {
    float hv[8];
    #pragma unroll
    for (int e = 0; e < 8; ++e)
      hv[e] = hin[((b * CH + lg * 8 + e) << 12) + n0 + nloc];
    u32x4 hh, hl2;
    #pragma unroll
    for (int e2 = 0; e2 < 4; ++e2) {
      u32 a_, b_;
      split2(hv[2 * e2], hv[2 * e2 + 1], a_, b_);
      hh[e2] = a_; hl2[e2] = b_;
    }
    ah_c = __builtin_bit_cast(s8v, hh);
    al_c = __builtin_bit_cast(s8v, hl2);
    const u16* cwp = cwb + l * 2048;
    cwh0 = *(const s8v*)(cwp + 0    + l6 * 8);
    cwh1 = *(const s8v*)(cwp + 512  + l6 * 8);
    cwl0 = *(const s8v*)(cwp + 1024 + l6 * 8);
    cwl1 = *(const s8v*)(cwp + 1536 + l6 * 8);
  }

  __syncthreads();

  f4v P0 = {0,0,0,0}, P1 = {0,0,0,0}, B0 = {0,0,0,0}, B1 = {0,0,0,0};
  f4v S1a0 = {0,0,0,0}, S1a1 = {0,0,0,0}, S1b0 = {0,0,0,0}, S1b1 = {0,0,0,0};
  if (wk == 0) {
    MF(ah_c, cwh0, P0); MF(ah_c, cwl0, P0); MF(al_c, cwh0, P0);
    MF(ah_c, cwh1, P1); MF(ah_c, cwl1, P1); MF(al_c, cwh1, P1);
    S1a0 = P0; S1a1 = P1;
  }

  const u16* fbb = fullB + (size_t)(b * KTI) * 4096 + l6 * 8;

  #pragma unroll
  for (int q = 0; q < 5; ++q) {
    int kt = ktbeg + q;
    if (kt >= ktend) break;
    const u16* bp = fbb + kt * 4096;
    s8v Frh0 = *(const s8v*)(bp + 0);
    s8v Frh1 = *(const s8v*)(bp + 512);
    s8v Frl0 = *(const s8v*)(bp + 1024);
    s8v Frl1 = *(const s8v*)(bp + 1536);
    s8v Fih0 = *(const s8v*)(bp + 2048);
    s8v Fih1 = *(const s8v*)(bp + 2560);
    s8v Fil0 = *(const s8v*)(bp + 3072);
    s8v Fil1 = *(const s8v*)(bp + 3584);

    const int mbase = (kt << 5) + (lg << 3);
    const int j = (mbase * 2731) >> 16;
    const int i0 = mbase - 24 * j;
    const float2 ey = eyv[q];
    u32x4 rh, rl, ih, il;
    #pragma unroll
    for (int e2 = 0; e2 < 4; ++e2) {
      float4 qq = *(const float4*)&exT[nloc][i0 + 2 * e2];
      float vr0 = qq.x * ey.x - qq.y * ey.y;
      float vi0 = qq.x * ey.y + qq.y * ey.x;
      float vr1 = qq.z * ey.x - qq.w * ey.y;
      float vi1 = qq.z * ey.y + qq.w * ey.x;
      u32 w0, w1, w2, w3;
      split2(vr0, vr1, w0, w1);
      split2(vi0, vi1, w2, w3);
      rh[e2] = w0; rl[e2] = w1; ih[e2] = w2; il[e2] = w3;
    }
    s8v arh = __builtin_bit_cast(s8v, rh), arl = __builtin_bit_cast(s8v, rl);
    s8v aih = __builtin_bit_cast(s8v, ih), ail = __builtin_bit_cast(s8v, il);
    u32x4 nh = rh ^ 0x80008000u, nl2 = rl ^ 0x80008000u;
    s8v narh = __builtin_bit_cast(s8v, nh), narl = __builtin_bit_cast(s8v, nl2);

    MF(arh, Frh0, P0); MF(arh, Frl0, P0); MF(arl, Frh0, P0);
    MF(aih, Fih0, P0); MF(aih, Fil0, P0); MF(ail, Fih0, P0);
    MF(arh, Frh1, P1); MF(arh, Frl1, P1); MF(arl, Frh1, P1);
    MF(aih, Fih1, P1); MF(aih, Fil1, P1); MF(ail, Fih1, P1);
    MF(aih, Frh0, B0); MF(aih, Frl0, B0); MF(ail, Frh0, B0);
    MF(narh, Fih0, B0); MF(narh, Fil0, B0); MF(narl, Fih0, B0);
    MF(aih, Frh1, B1); MF(aih, Frl1, B1); MF(ail, Frh1, B1);
    MF(narh, Fih1, B1); MF(narh, Fil1, B1); MF(narl, Fih1, B1);
    if (kt == 0) {
      s8v z = {0,0,0,0,0,0,0,0};
      bool live = (lg < 3);
      s8v zrh = live ? arh : z, zrl = live ? arl : z;
      s8v zih = live ? aih : z, zil = live ? ail : z;
      s8v znrh = live ? narh : z, znrl = live ? narl : z;
      MF(zrh, Frh0, S1a0); MF(zrh, Frl0, S1a0); MF(zrl, Frh0, S1a0);
      MF(zih, Fih0, S1a0); MF(zih, Fil0, S1a0); MF(zil, Fih0, S1a0);
      MF(zrh, Frh1, S1a1); MF(zrh, Frl1, S1a1); MF(zrl, Frh1, S1a1);
      MF(zih, Fih1, S1a1); MF(zih, Fil1, S1a1); MF(zil, Fih1, S1a1);
      MF(zih, Frh0, S1b0); MF(zih, Frl0, S1b0); MF(zil, Frh0, S1b0);
      MF(znrh, Fih0, S1b0); MF(znrh, Fil0, S1b0); MF(znrl, Fih0, S1b0);
      MF(zih, Frh1, S1b1); MF(zih, Frl1, S1b1); MF(zil, Frh1, S1b1);
      MF(znrh, Fih1, S1b1); MF(znrh, Fil1, S1b1); MF(znrl, Fih1, S1b1);
    }
  }

  if (wk == 1) {
    int row = wr * 64 + l6;
    *(f4v*)&red[row][0]  = P0;
    *(f4v*)&red[row][4]  = P1;
    *(f4v*)&red[row][8]  = B0;
    *(f4v*)&red[row][12] = B1;
  }
  __syncthreads();
  if (wk == 0) {
    int row = wr * 64 + l6;
    P0 += *(const f4v*)&red[row][0];
    P1 += *(const f4v*)&red[row][4];
    B0 += *(const f4v*)&red[row][8];
    B1 += *(const f4v*)&red[row][12];

    float cb0 = cb[l * CH + lr];
    float cb1 = cb[l * CH + 16 + lr];
    #pragma unroll
    for (int r = 0; r < 4; ++r) {
      int nn = wr * 16 + lg * 4 + r;
      float2 e1 = exT[nn][1];                 // SCALE * exp(-i*xs_nn)
      float cs = e1.x * INV_S, sn = -e1.y * INV_S;
      float a20 = P0[r] - S1a0[r], a21 = P1[r] - S1a1[r];
      float b20 = B0[r] - S1b0[r], b21 = B1[r] - S1b1[r];
      float U0r = cs * a20 + sn * b20;
      float U1r = cs * a21 + sn * b21;
      float u1s = __shfl_xor(U1r, 15, 64);
      float u0s = __shfl_xor(U0r, 15, 64);
      float v0 = P0[r] + u1s + cb0;
      float v1 = P1[r] + u0s + cb1;
      if (doGelu) { v0 = gelu_f(v0); v1 = gelu_f(v1); }
      hout[((b * CH + lr) << 12) + n0 + nn] = v0;
      hout[((b * CH + 16 + lr) << 12) + n0 + nn] = v1;
    }
  }
}

// ---------------- final: fc1 (MFMA) + gelu + fc2 ----------------
__global__ __launch_bounds__(256) void k_final_m(const float* __restrict__ hin,
    const u16* __restrict__ f1b, const float* __restrict__ fc1b_,
    const float* __restrict__ fc2w, const float* __restrict__ fc2b,
    float* __restrict__ out) {
  const int b = blockIdx.y;
  const int n0 = blockIdx.x << 6;
  const int t = threadIdx.x, w = t >> 6, l6 = t & 63;
  const int lr = l6 & 15, lg = l6 >> 4;
  const int nloc = w * 16 + lr;

  // A-frag: h[nloc][c = lg*8 + e] (direct gather)
  s8v ah, al;
  {
    float hv[8];
    #pragma unroll
    for (int e = 0; e < 8; ++e)
      hv[e] = hin[((b * CH + lg * 8 + e) << 12) + n0 + nloc];
    u32x4 hh, hl2;
    #pragma unroll
    for (int e2 = 0; e2 < 4; ++e2) {
      u32 a_, b_;
      split2(hv[2 * e2], hv[2 * e2 + 1], a_, b_);
      hh[e2] = a_; hl2[e2] = b_;
    }
    ah = __builtin_bit_cast(s8v, hh);
    al = __builtin_bit_cast(s8v, hl2);
  }

  float acc[4] = {0.f, 0.f, 0.f, 0.f};
  #pragma unroll
  for (int tt = 0; tt < 8; ++tt) {
    s8v Bh = *(const s8v*)(f1b + tt * 512 + l6 * 8);
    s8v Bl = *(const s8v*)(f1b + (8 + tt) * 512 + l6 * 8);
    f4v D = {0.f, 0.f, 0.f, 0.f};
    MF(ah, Bh, D); MF(ah, Bl, D); MF(al, Bh, D);
    float b1v = fc1b_[tt * 16 + lr];
    float w2v = fc2w[tt * 16 + lr];
    #pragma unroll
    for (int r = 0; r < 4; ++r) acc[r] += gelu_f(D[r] + b1v) * w2v;
  }
  float ob = fc2b[0];
  #pragma unroll
  for (int r = 0; r < 4; ++r) {
    float v = acc[r];
    v += __shfl_xor(v, 1, 64);
    v += __shfl_xor(v, 2, 64);
    v += __shfl_xor(v, 4, 64);
    v += __shfl_xor(v, 8, 64);
    if (lr == 0) out[(b << 12) + n0 + w * 16 + lg * 4 + r] = v + ob;
  }
}

extern "C" void kernel_launch(void* const* d_in, const int* in_sizes, int n_in,
                              void* d_out, int out_size, void* d_ws, size_t ws_size,
                              hipStream_t stream) {
  const float* pos   = (const float*)d_in[0];
  const float* fc0_w = (const float*)d_in[1];
  const float* fc0_b = (const float*)d_in[2];
  const float* sw1r  = (const float*)d_in[3];
  const float* sw1i  = (const float*)d_in[4];
  const float* sw2r  = (const float*)d_in[5];
  const float* sw2i  = (const float*)d_in[6];
  const float* cw    = (const float*)d_in[7];
  const float* cb    = (const float*)d_in[8];
  const float* fc1_w = (const float*)d_in[9];
  const float* fc1_b = (const float*)d_in[10];
  const float* fc2_w = (const float*)d_in[11];
  const float* fc2_b = (const float*)d_in[12];
  float* out = (float*)d_out;
  float* ws = (float*)d_ws;

  size_t off = 0;
  float* partials = ws;                 off += 256;
  float* scal = ws + off;               off += 16;
  float2* ExI = (float2*)(ws + off);    off += (size_t)BB * MX * NPT * 2;
  float2* EyI = (float2*)(ws + off);    off += (size_t)BB * MYK * NPT * 2;
  float* hA  = ws + off;                off += (size_t)BB * CH * NPT;
  float* hB  = ws + off;                off += (size_t)BB * CH * NPT;
  float* xfr = ws + off;                off += (size_t)NS * BB * NF * CH;
  float* xfi = ws + off;                off += (size_t)NS * BB * NF * CH;
  u16*  fullB = (u16*)(ws + off);       off += (size_t)BB * KTI * 4096 / 2;
  float* wtr = ws + off;                off += (size_t)4 * NF * CH * CH;
  float* wti = ws + off;                off += (size_t)4 * NF * CH * CH;
  u16*  cwb = (u16*)(ws + off);         off += 4096;
  u16*  f1b = (u16*)(ws + off);         off += 4096;   // 8192 u16
  // total ~17.2M floats (~69 MB)

  k_minmax1<<<64, 256, 0, stream>>>(pos, partials);
  k_minmax2<<<1, 64, 0, stream>>>(partials, scal);
  k_setup<<<(BB * NPT) / 256, 256, 0, stream>>>(pos, fc0_w, fc0_b, scal, ExI, EyI, hA);
  k_wtcw<<<261, 256, 0, stream>>>(sw1r, sw1i, sw2r, sw2i, wtr, wti, cw, cwb, fc1_w, f1b);

  for (int l = 0; l < 4; ++l) {
    const float* hin = (l & 1) ? hB : hA;
    float* hout = (l & 1) ? hA : hB;
    k_fwd_m<<<dim3(3, BB, NS), 384, 0, stream>>>(hin, ExI, EyI, xfr, xfi);
    k_mix<<<dim3(NF / 4, BB), 256, 0, stream>>>(xfr, xfi, wtr, wti, fullB, l);
    k_inv_m<<<dim3(64, BB), 512, 0, stream>>>(hin, ExI, EyI, fullB, cwb, cb,
                                              hout, l, (l < 3) ? 1 : 0);
  }
  k_final_m<<<dim3(64, BB), 256, 0, stream>>>(hA, f1b, fc1_b, fc2_w, fc2_b, out);
}